// Round 2
// baseline (892.899 us; speedup 1.0000x reference)
//
#include <hip/hip_runtime.h>
#include <hip/hip_bf16.h>
#include <math.h>

// ---------------------------------------------------------------------------
// DeepseekMoE: T=16384 tokens, D=128, E=64 experts top-6, M=80, shared MS=160.
// Shared expert folded in as experts 64,65 (MS = 2*80) with weight 1.0.
// Device dtype auto-detected (f32 vs bf16); MFMA path uses canonical bf16.
// ---------------------------------------------------------------------------

typedef unsigned short ushort_t;
typedef __attribute__((ext_vector_type(8))) short bf16x8;   // 8 bf16 = 4 VGPR
typedef __attribute__((ext_vector_type(4))) float f32x4;

#define EALL  66

// workspace byte offsets
#define OFF_TOPKI 16384
#define OFF_TOPKW (OFF_TOPKI + 98304*4)
#define OFF_PERM  (OFF_TOPKW + 98304*4)
#define OFF_PERMW (OFF_PERM  + 98304*4)
#define OFF_YBUF  (OFF_PERMW + 98304*4)            // float[T*D] = 8 MB
#define OFF_WGT   (OFF_YBUF + 16384*128*4)          // bf16 [66][80][128]
#define OFF_WUT   (OFF_WGT + 66*80*128*2)
#define OFF_WDT   (OFF_WUT + 66*80*128*2)           // bf16 [66][128][80]
#define OFF_XB    (OFF_WDT + 66*80*128*2)           // bf16 [16384][128]
// int ws indices (first 1024 B zeroed each launch):
//   Wi[0..63]=cnt, Wi[64..128]=excl, Wi[129..192]=cur, Wi[193]=nwork,
//   Wi[195]=f32mode, Wi[256..]=worklist

__device__ __forceinline__ float bf2f(ushort_t u) {
    unsigned int x = ((unsigned int)u) << 16;
    float f; __builtin_memcpy(&f, &x, 4); return f;
}
__device__ __forceinline__ ushort_t f2bf(float f) {
    unsigned int x; __builtin_memcpy(&x, &f, 4);
    unsigned int r = (x + 0x7fffu + ((x >> 16) & 1u)) >> 16;   // RNE
    return (ushort_t)r;
}
// dual-dtype scalar load
__device__ __forceinline__ float ldin(const void* p, int i, int f32m) {
    return f32m ? ((const float*)p)[i] : bf2f(((const ushort_t*)p)[i]);
}

// ---------------------------------------------------------------------------
// Detect input dtype from gate_w: |gw| < 2^-3 so bf16 halves never have
// exponent field >= 0x7C; f32 mantissa low-halves are ~uniform (do ~52%).
// ---------------------------------------------------------------------------
__global__ __launch_bounds__(64) void k_detect(const ushort_t* gw, int* Wi) {
    int lane = threadIdx.x;
    int cnt = 0;
    #pragma unroll
    for (int j = 0; j < 4; ++j) {
        ushort_t u = gw[lane * 4 + j];
        if (((u >> 7) & 0xFF) >= 0x7C) cnt++;
    }
    #pragma unroll
    for (int off = 32; off; off >>= 1) cnt += __shfl_xor(cnt, off);
    if (lane == 0) Wi[195] = (cnt >= 8) ? 1 : 0;
}

// ---------------------------------------------------------------------------
// Canonicalize x -> bf16 xB.  8 elements per thread.  grid 1024x256.
// ---------------------------------------------------------------------------
__global__ __launch_bounds__(256) void k_cvt(const void* x, ushort_t* xB, const int* Wi) {
    int i = blockIdx.x * 256 + threadIdx.x;          // i < 262144, 8 elems each
    int f32m = Wi[195];
    ushort_t o[8];
    if (f32m) {
        const float4* xf = (const float4*)x;
        float4 a = xf[i * 2], b = xf[i * 2 + 1];
        o[0]=f2bf(a.x); o[1]=f2bf(a.y); o[2]=f2bf(a.z); o[3]=f2bf(a.w);
        o[4]=f2bf(b.x); o[5]=f2bf(b.y); o[6]=f2bf(b.z); o[7]=f2bf(b.w);
        *(uint4*)(xB + i * 8) = *(const uint4*)o;
    } else {
        *(uint4*)(xB + i * 8) = ((const uint4*)x)[i];
    }
}

// ---------------------------------------------------------------------------
// Prep: transpose weights.  wgT/wuT[e][m][d] <- wg[e][d][m];  wdT[e][d][m] <- wd[e][m][d]
// ---------------------------------------------------------------------------
__global__ __launch_bounds__(256) void k_prep(const void* wg, const void* wu,
        const void* wd, const void* swg, const void* swu, const void* swd,
        ushort_t* wgT, ushort_t* wuT, ushort_t* wdT, const int* Wi) {
    __shared__ float lds[128 * 81];   // also viewed as [80][129]
    int bid = blockIdx.x, tid = threadIdx.x;
    int mat = bid / EALL, e = bid % EALL;
    int f32m = Wi[195];
    if (mat < 2) {
        const void* src  = (mat == 0) ? wg  : wu;
        const void* ssrc = (mat == 0) ? swg : swu;
        for (int i = tid; i < 10240; i += 256) {
            int d = i / 80, m = i % 80;
            float v = (e < 64) ? ldin(src, e * 10240 + i, f32m)
                               : ldin(ssrc, d * 160 + (e - 64) * 80 + m, f32m);
            lds[d * 81 + m] = v;
        }
        __syncthreads();
        ushort_t* dst = ((mat == 0) ? wgT : wuT) + e * 10240;
        for (int o = tid; o < 10240; o += 256) {
            int m = o >> 7, d = o & 127;
            dst[o] = f2bf(lds[d * 81 + m]);
        }
    } else {
        for (int i = tid; i < 10240; i += 256) {
            float v = (e < 64) ? ldin(wd, e * 10240 + i, f32m)
                               : ldin(swd, (e - 64) * 10240 + i, f32m);
            int m = i >> 7, d = i & 127;
            lds[m * 129 + d] = v;
        }
        __syncthreads();
        ushort_t* dst = wdT + e * 10240;
        for (int o = tid; o < 10240; o += 256) {
            int d = o / 80, m = o % 80;
            dst[o] = f2bf(lds[m * 129 + d]);
        }
    }
}

// ---------------------------------------------------------------------------
// Gating: wave-per-token at NATIVE precision (so top-k matches reference).
// lane e owns expert e. softmax + top-6 (lowest-index tie-break) + renorm.
// ---------------------------------------------------------------------------
__global__ __launch_bounds__(256) void k_gate(const void* x, const void* gw,
        int* topk_i, float* topk_w, int* Wi) {
    __shared__ float gwl[64 * 129];
    __shared__ float xl[4][128];
    int tid = threadIdx.x;
    int f32m = Wi[195];
    for (int i = tid; i < 8192; i += 256)
        gwl[(i >> 7) * 129 + (i & 127)] = ldin(gw, i, f32m);
    __syncthreads();
    int wv = tid >> 6, lane = tid & 63;
    for (int it = 0; it < 4; ++it) {
        int t = it * 4096 + blockIdx.x * 4 + wv;
        if (f32m) {
            float2 v = ((const float2*)((const float*)x + t * 128))[lane];
            xl[wv][lane * 2] = v.x; xl[wv][lane * 2 + 1] = v.y;
        } else {
            unsigned int pr = *(const unsigned int*)((const ushort_t*)x + t * 128 + lane * 2);
            xl[wv][lane * 2]     = bf2f((ushort_t)(pr & 0xffffu));
            xl[wv][lane * 2 + 1] = bf2f((ushort_t)(pr >> 16));
        }
        __syncthreads();
        float acc = 0.f;
        #pragma unroll
        for (int d = 0; d < 128; ++d)
            acc = fmaf(xl[wv][d], gwl[lane * 129 + d], acc);
        // softmax over 64 lanes
        float mx = acc;
        #pragma unroll
        for (int off = 32; off; off >>= 1) mx = fmaxf(mx, __shfl_xor(mx, off));
        float p = expf(acc - mx);
        float sm = p;
        #pragma unroll
        for (int off = 32; off; off >>= 1) sm += __shfl_xor(sm, off);
        float sc = p / sm;
        float cur = sc;
        float wk[6]; int ik[6];
        #pragma unroll
        for (int k = 0; k < 6; ++k) {
            float bv = cur; int bi = lane;
            #pragma unroll
            for (int off = 1; off < 64; off <<= 1) {
                float ov = __shfl_xor(bv, off); int oi = __shfl_xor(bi, off);
                if (ov > bv || (ov == bv && oi < bi)) { bv = ov; bi = oi; }
            }
            wk[k] = bv; ik[k] = bi;
            if (lane == bi) cur = -INFINITY;
        }
        if (lane == 0) {
            float den = wk[0] + wk[1] + wk[2] + wk[3] + wk[4] + wk[5] + 1e-20f;
            #pragma unroll
            for (int k = 0; k < 6; ++k) {
                topk_i[t * 6 + k] = ik[k];
                topk_w[t * 6 + k] = wk[k] / den;
                atomicAdd(&Wi[ik[k]], 1);
            }
        }
        __syncthreads();
    }
}

// ---------------------------------------------------------------------------
// Scan: exclusive offsets + bounded worklist. Routed chunks <= 1600, + 512 shared.
// ---------------------------------------------------------------------------
__global__ __launch_bounds__(256) void k_scan(int* Wi) {
    __shared__ int chx[65];
    int tid = threadIdx.x;
    if (tid == 0) {
        int s = 0, cs = 0;
        for (int e = 0; e < 64; ++e) {
            Wi[64 + e] = s; s += Wi[e];
            chx[e] = cs; cs += (Wi[e] + 63) >> 6;
        }
        Wi[128] = s;
        chx[64] = cs;
        Wi[193] = cs + 512;   // nwork
    }
    __syncthreads();
    if (tid < 64) {
        int e = tid, nc = (Wi[e] + 63) >> 6, b = chx[e];
        for (int c = 0; c < nc; ++c) Wi[256 + b + c] = (e << 16) | c;
    }
    int R = chx[64];
    for (int j = tid; j < 512; j += 256)
        Wi[256 + R + j] = ((64 + (j >> 8)) << 16) | (j & 255);
}

// ---------------------------------------------------------------------------
// Scatter tokens into per-expert buckets.
// ---------------------------------------------------------------------------
__global__ __launch_bounds__(256) void k_scatter(const int* topk_i, const float* topk_w,
        const int* excl, int* cur, int* perm, float* permw) {
    int i = blockIdx.x * 256 + threadIdx.x;
    if (i >= 98304) return;
    int e = topk_i[i];
    int p = excl[e] + atomicAdd(&cur[e], 1);
    perm[p]  = i / 6;
    permw[p] = topk_w[i];
}

// ---------------------------------------------------------------------------
// Expert MLP: per (expert, 64-token chunk).  4 waves.
// LDS tiles swizzled: byte = row*256 + (colByte ^ ((row&7)<<4))  (16B granular).
// GEMM1: h = silu(x@wgT^T)*(x@wuT^T);  GEMM2 (swapped): y^T = wdT @ h^T, K->96.
// ---------------------------------------------------------------------------
__global__ __launch_bounds__(256) void k_expert(const ushort_t* x, const ushort_t* wgT,
        const ushort_t* wuT, const ushort_t* wdT, const int* Wi, const int* perm,
        const float* permw, float* ybuf) {
    __shared__ char smem[53760];
    char* xl   = smem;
    char* wbuf = smem + 16384;
    char* hl   = smem + 36864;
    int*   tokL = (int*)(smem + 53248);
    float* wtL  = (float*)(smem + 53504);

    if (blockIdx.x >= Wi[193]) return;
    int entry = Wi[256 + blockIdx.x];
    int e = entry >> 16, c = entry & 0xffff;
    int tid = threadIdx.x, lid = tid & 63, wv = tid >> 6;
    int nrows = 64, base = 0;
    if (e < 64) {
        int n = Wi[e]; base = Wi[64 + e];
        nrows = n - c * 64; if (nrows > 64) nrows = 64;
    }

    if (tid < 64) {
        int r = tid, t = 0; float w = 0.f;
        if (r < nrows) {
            if (e < 64) { t = perm[base + c * 64 + r]; w = permw[base + c * 64 + r]; }
            else        { t = c * 64 + r; w = 1.0f; }
        }
        tokL[r] = t; wtL[r] = w;
    }

    // stage x tile (zero-pad invalid rows)
    #pragma unroll
    for (int u = tid; u < 1024; u += 256) {
        int r = u >> 4, ch = u & 15;
        uint4 v = {0u, 0u, 0u, 0u};
        if (r < nrows) {
            int t = (e < 64) ? perm[base + c * 64 + r] : (c * 64 + r);
            v = *(const uint4*)(x + t * 128 + ch * 8);
        }
        *(uint4*)(xl + r * 256 + ((ch * 16) ^ ((r & 7) << 4))) = v;
    }
    // stage wgT (80 rows x 128)
    {
        const ushort_t* wsrc = wgT + e * 10240;
        #pragma unroll
        for (int u = tid; u < 1280; u += 256) {
            int r = u >> 4, ch = u & 15;
            uint4 v = *(const uint4*)(wsrc + r * 128 + ch * 8);
            *(uint4*)(wbuf + r * 256 + ((ch * 16) ^ ((r & 7) << 4))) = v;
        }
    }
    __syncthreads();

    int arow = wv * 16 + (lid & 15);
    int kg = (lid >> 4) * 16;   // lane-group k byte offset
    bf16x8 a[4];
    #pragma unroll
    for (int k = 0; k < 4; ++k)
        a[k] = *(const bf16x8*)(xl + arow * 256 + (((k * 64) + kg) ^ ((arow & 7) << 4)));

    f32x4 accg[5], accu[5];
    #pragma unroll
    for (int mi = 0; mi < 5; ++mi) {
        f32x4 acc = {0.f, 0.f, 0.f, 0.f};
        int brow = mi * 16 + (lid & 15);
        #pragma unroll
        for (int k = 0; k < 4; ++k) {
            bf16x8 b = *(const bf16x8*)(wbuf + brow * 256 + (((k * 64) + kg) ^ ((brow & 7) << 4)));
            acc = __builtin_amdgcn_mfma_f32_16x16x32_bf16(a[k], b, acc, 0, 0, 0);
        }
        accg[mi] = acc;
    }
    __syncthreads();
    // restage with wuT
    {
        const ushort_t* wsrc = wuT + e * 10240;
        #pragma unroll
        for (int u = tid; u < 1280; u += 256) {
            int r = u >> 4, ch = u & 15;
            uint4 v = *(const uint4*)(wsrc + r * 128 + ch * 8);
            *(uint4*)(wbuf + r * 256 + ((ch * 16) ^ ((r & 7) << 4))) = v;
        }
    }
    __syncthreads();
    #pragma unroll
    for (int mi = 0; mi < 5; ++mi) {
        f32x4 acc = {0.f, 0.f, 0.f, 0.f};
        int brow = mi * 16 + (lid & 15);
        #pragma unroll
        for (int k = 0; k < 4; ++k) {
            bf16x8 b = *(const bf16x8*)(wbuf + brow * 256 + (((k * 64) + kg) ^ ((brow & 7) << 4)));
            acc = __builtin_amdgcn_mfma_f32_16x16x32_bf16(a[k], b, acc, 0, 0, 0);
        }
        accu[mi] = acc;
    }

    // h = silu(g) * u -> hl (bf16, swizzled), then zero-pad K columns 80..95
    #pragma unroll
    for (int mi = 0; mi < 5; ++mi) {
        #pragma unroll
        for (int rg = 0; rg < 4; ++rg) {
            float g = accg[mi][rg], uu = accu[mi][rg];
            float h = (g / (1.f + expf(-g))) * uu;
            int row = wv * 16 + (lid >> 4) * 4 + rg;
            int cb = (mi * 16 + (lid & 15)) * 2;
            *(ushort_t*)(hl + row * 256 + (cb ^ ((row & 7) << 4))) = f2bf(h);
        }
    }
    if (tid < 128) {
        int r = tid >> 1, ch = 10 + (tid & 1);
        uint4 z = {0u, 0u, 0u, 0u};
        *(uint4*)(hl + r * 256 + ((ch * 16) ^ ((r & 7) << 4))) = z;
    }
    __syncthreads();

    // down projection in two 64-row halves of wdT
    #pragma unroll
    for (int ph = 0; ph < 2; ++ph) {
        #pragma unroll
        for (int u = tid; u < 768; u += 256) {
            int r = u / 12, ch = u % 12;
            uint4 v = {0u, 0u, 0u, 0u};
            if (ch < 10) v = *(const uint4*)(wdT + (e * 128 + ph * 64 + r) * 80 + ch * 8);
            *(uint4*)(wbuf + r * 256 + ((ch * 16) ^ ((r & 7) << 4))) = v;
        }
        __syncthreads();
        int drow = wv * 16 + (lid & 15);
        bf16x8 ad[3];
        #pragma unroll
        for (int k = 0; k < 3; ++k)
            ad[k] = *(const bf16x8*)(wbuf + drow * 256 + (((k * 64) + kg) ^ ((drow & 7) << 4)));
        #pragma unroll
        for (int tf = 0; tf < 4; ++tf) {
            int brow = tf * 16 + (lid & 15);
            f32x4 acc = {0.f, 0.f, 0.f, 0.f};
            #pragma unroll
            for (int k = 0; k < 3; ++k) {
                bf16x8 b = *(const bf16x8*)(hl + brow * 256 + (((k * 64) + kg) ^ ((brow & 7) << 4)));
                acc = __builtin_amdgcn_mfma_f32_16x16x32_bf16(ad[k], b, acc, 0, 0, 0);
            }
            int rloc = tf * 16 + (lid & 15);
            if (rloc < nrows) {
                int t = tokL[rloc]; float w = wtL[rloc];
                int dbase = ph * 64 + wv * 16 + (lid >> 4) * 4;
                #pragma unroll
                for (int rg = 0; rg < 4; ++rg)
                    atomicAdd(&ybuf[t * 128 + dbase + rg], acc[rg] * w);
            }
        }
        __syncthreads();
    }
}

// ---------------------------------------------------------------------------
__global__ __launch_bounds__(256) void k_final(const float* ybuf, void* out, const int* Wi) {
    int i = blockIdx.x * 256 + threadIdx.x;
    int f32m = Wi[195];
    float4 v = ((const float4*)ybuf)[i];
    if (f32m) {
        ((float4*)out)[i] = v;
    } else {
        ushort4 o;
        o.x = f2bf(v.x); o.y = f2bf(v.y); o.z = f2bf(v.z); o.w = f2bf(v.w);
        ((ushort4*)out)[i] = o;
    }
}

// ---------------------------------------------------------------------------
extern "C" void kernel_launch(void* const* d_in, const int* in_sizes, int n_in,
                              void* d_out, int out_size, void* d_ws, size_t ws_size,
                              hipStream_t stream) {
    (void)in_sizes; (void)n_in; (void)out_size; (void)ws_size;
    const void* x   = d_in[0];
    const void* gw  = d_in[1];
    const void* wg  = d_in[2];
    const void* wu  = d_in[3];
    const void* wd  = d_in[4];
    const void* swg = d_in[5];
    const void* swu = d_in[6];
    const void* swd = d_in[7];

    char* ws = (char*)d_ws;
    int*      Wi     = (int*)d_ws;
    int*      topk_i = (int*)(ws + OFF_TOPKI);
    float*    topk_w = (float*)(ws + OFF_TOPKW);
    int*      perm   = (int*)(ws + OFF_PERM);
    float*    permw  = (float*)(ws + OFF_PERMW);
    float*    ybuf   = (float*)(ws + OFF_YBUF);
    ushort_t* wgT    = (ushort_t*)(ws + OFF_WGT);
    ushort_t* wuT    = (ushort_t*)(ws + OFF_WUT);
    ushort_t* wdT    = (ushort_t*)(ws + OFF_WDT);
    ushort_t* xB     = (ushort_t*)(ws + OFF_XB);

    hipMemsetAsync(d_ws, 0, 1024, stream);
    hipMemsetAsync(ybuf, 0, 16384 * 128 * 4, stream);

    k_detect<<<1, 64, 0, stream>>>((const ushort_t*)gw, Wi);
    k_cvt<<<1024, 256, 0, stream>>>(x, xB, Wi);
    k_prep<<<3 * EALL, 256, 0, stream>>>(wg, wu, wd, swg, swu, swd, wgT, wuT, wdT, Wi);
    k_gate<<<1024, 256, 0, stream>>>(x, gw, topk_i, topk_w, Wi);
    k_scan<<<1, 256, 0, stream>>>(Wi);
    k_scatter<<<384, 256, 0, stream>>>(topk_i, topk_w, Wi + 64, Wi + 129, perm, permw);
    k_expert<<<2112, 256, 0, stream>>>(xB, wgT, wuT, wdT, Wi, perm, permw, ybuf);
    k_final<<<2048, 256, 0, stream>>>(ybuf, d_out, Wi);
}

// Round 3
// 375.167 us; speedup vs baseline: 2.3800x; 2.3800x over previous
//
#include <hip/hip_runtime.h>
#include <hip/hip_bf16.h>
#include <math.h>

// ---------------------------------------------------------------------------
// DeepseekMoE: T=16384 tokens, D=128, E=64 experts top-6, M=80, shared MS=160.
// Shared expert folded in as experts 64,65 (MS = 2*80) with weight 1.0.
// Device dtype auto-detected (f32 vs bf16); MFMA path uses canonical bf16.
// R2: removed all contended global atomics (gate histogram + scatter) —
//     per-block LDS histograms + 1-block shuffle scan + block-local scatter.
// ---------------------------------------------------------------------------

typedef unsigned short ushort_t;
typedef __attribute__((ext_vector_type(8))) short bf16x8;   // 8 bf16 = 4 VGPR
typedef __attribute__((ext_vector_type(4))) float f32x4;

#define EALL  66

// workspace byte offsets
#define OFF_TOPKI 16384
#define OFF_TOPKW (OFF_TOPKI + 98304*4)
#define OFF_PERM  (OFF_TOPKW + 98304*4)
#define OFF_PERMW (OFF_PERM  + 98304*4)
#define OFF_YBUF  (OFF_PERMW + 98304*4)            // float[T*D] = 8 MB
#define OFF_WGT   (OFF_YBUF + 16384*128*4)          // bf16 [66][80][128]
#define OFF_WUT   (OFF_WGT + 66*80*128*2)
#define OFF_WDT   (OFF_WUT + 66*80*128*2)           // bf16 [66][128][80]
#define OFF_XB    (OFF_WDT + 66*80*128*2)           // bf16 [16384][128]
#define OFF_HIST  (OFF_XB + 16384*128*2)            // int [64][256]
#define OFF_BOFF  (OFF_HIST + 65536)                // int [64][256]
// int ws indices: Wi[0..63]=cnt, Wi[64..128]=excl, Wi[193]=nwork,
//   Wi[195]=f32mode, Wi[256..]=worklist (<=2112 entries)

__device__ __forceinline__ float bf2f(ushort_t u) {
    unsigned int x = ((unsigned int)u) << 16;
    float f; __builtin_memcpy(&f, &x, 4); return f;
}
__device__ __forceinline__ ushort_t f2bf(float f) {
    unsigned int x; __builtin_memcpy(&x, &f, 4);
    unsigned int r = (x + 0x7fffu + ((x >> 16) & 1u)) >> 16;   // RNE
    return (ushort_t)r;
}
// dual-dtype scalar load
__device__ __forceinline__ float ldin(const void* p, int i, int f32m) {
    return f32m ? ((const float*)p)[i] : bf2f(((const ushort_t*)p)[i]);
}

// ---------------------------------------------------------------------------
// Detect input dtype from gate_w: |gw| < 2^-3 so bf16 halves never have
// exponent field >= 0x7C; f32 mantissa low-halves are ~uniform (~52% do).
// ---------------------------------------------------------------------------
__global__ __launch_bounds__(64) void k_detect(const ushort_t* gw, int* Wi) {
    int lane = threadIdx.x;
    int cnt = 0;
    #pragma unroll
    for (int j = 0; j < 4; ++j) {
        ushort_t u = gw[lane * 4 + j];
        if (((u >> 7) & 0xFF) >= 0x7C) cnt++;
    }
    #pragma unroll
    for (int off = 32; off; off >>= 1) cnt += __shfl_xor(cnt, off);
    if (lane == 0) Wi[195] = (cnt >= 8) ? 1 : 0;
}

// ---------------------------------------------------------------------------
// Prep: transpose weights.  wgT/wuT[e][m][d] <- wg[e][d][m];  wdT[e][d][m] <- wd[e][m][d]
// ---------------------------------------------------------------------------
__global__ __launch_bounds__(256) void k_prep(const void* wg, const void* wu,
        const void* wd, const void* swg, const void* swu, const void* swd,
        ushort_t* wgT, ushort_t* wuT, ushort_t* wdT, const int* Wi) {
    __shared__ float lds[128 * 81];   // also viewed as [80][129]
    int bid = blockIdx.x, tid = threadIdx.x;
    int mat = bid / EALL, e = bid % EALL;
    int f32m = Wi[195];
    if (mat < 2) {
        const void* src  = (mat == 0) ? wg  : wu;
        const void* ssrc = (mat == 0) ? swg : swu;
        for (int i = tid; i < 10240; i += 256) {
            int d = i / 80, m = i % 80;
            float v = (e < 64) ? ldin(src, e * 10240 + i, f32m)
                               : ldin(ssrc, d * 160 + (e - 64) * 80 + m, f32m);
            lds[d * 81 + m] = v;
        }
        __syncthreads();
        ushort_t* dst = ((mat == 0) ? wgT : wuT) + e * 10240;
        for (int o = tid; o < 10240; o += 256) {
            int m = o >> 7, d = o & 127;
            dst[o] = f2bf(lds[d * 81 + m]);
        }
    } else {
        for (int i = tid; i < 10240; i += 256) {
            float v = (e < 64) ? ldin(wd, e * 10240 + i, f32m)
                               : ldin(swd, (e - 64) * 10240 + i, f32m);
            int m = i >> 7, d = i & 127;
            lds[m * 129 + d] = v;
        }
        __syncthreads();
        ushort_t* dst = wdT + e * 10240;
        for (int o = tid; o < 10240; o += 256) {
            int d = o / 80, m = o % 80;
            dst[o] = f2bf(lds[m * 129 + d]);
        }
    }
}

// ---------------------------------------------------------------------------
// Gating: 256 blocks x 64 tokens. Wave wv handles 16 tokens; lane = expert.
// f32 dot (matches reference top-k), softmax + top-6 + renorm.
// No global atomics: per-block LDS histogram -> histPart[e][b] plain store.
// Also emits xB (bf16 canonical x) as a side product.
// ---------------------------------------------------------------------------
__global__ __launch_bounds__(256) void k_gate(const void* x, const void* gw,
        ushort_t* xB, int* topk_i, float* topk_w, int* histPart, const int* Wi) {
    __shared__ float gwl[64 * 130];
    __shared__ float xl[4][128];
    __shared__ int histL[64];
    int tid = threadIdx.x, b = blockIdx.x;
    int f32m = Wi[195];
    for (int i = tid; i < 8192; i += 256)
        gwl[(i >> 7) * 130 + (i & 127)] = ldin(gw, i, f32m);
    if (tid < 64) histL[tid] = 0;
    __syncthreads();
    int wv = tid >> 6, lane = tid & 63;
    for (int q = 0; q < 16; ++q) {
        int t = b * 64 + wv * 16 + q;
        float xv0, xv1;
        if (f32m) {
            float2 v = ((const float2*)((const float*)x + t * 128))[lane];
            xv0 = v.x; xv1 = v.y;
        } else {
            unsigned int pr = *(const unsigned int*)((const ushort_t*)x + t * 128 + lane * 2);
            xv0 = bf2f((ushort_t)(pr & 0xffffu));
            xv1 = bf2f((ushort_t)(pr >> 16));
        }
        float2 xw; xw.x = xv0; xw.y = xv1;
        *(float2*)&xl[wv][lane * 2] = xw;
        unsigned int packed = (unsigned int)f2bf(xv0) | ((unsigned int)f2bf(xv1) << 16);
        *(unsigned int*)(xB + t * 128 + lane * 2) = packed;
        float acc = 0.f;
        #pragma unroll
        for (int d2 = 0; d2 < 64; ++d2) {
            float2 xv = *(const float2*)&xl[wv][d2 * 2];
            float2 gv = *(const float2*)&gwl[lane * 130 + d2 * 2];
            acc = fmaf(xv.x, gv.x, acc);
            acc = fmaf(xv.y, gv.y, acc);
        }
        // softmax over 64 lanes
        float mx = acc;
        #pragma unroll
        for (int off = 32; off; off >>= 1) mx = fmaxf(mx, __shfl_xor(mx, off));
        float p = expf(acc - mx);
        float sm = p;
        #pragma unroll
        for (int off = 32; off; off >>= 1) sm += __shfl_xor(sm, off);
        float sc = p / sm;
        float cur = sc;
        float wk[6]; int ik[6];
        #pragma unroll
        for (int k = 0; k < 6; ++k) {
            float bv = cur; int bi = lane;
            #pragma unroll
            for (int off = 1; off < 64; off <<= 1) {
                float ov = __shfl_xor(bv, off); int oi = __shfl_xor(bi, off);
                if (ov > bv || (ov == bv && oi < bi)) { bv = ov; bi = oi; }
            }
            wk[k] = bv; ik[k] = bi;
            if (lane == bi) cur = -INFINITY;
        }
        if (lane == 0) {
            float den = wk[0] + wk[1] + wk[2] + wk[3] + wk[4] + wk[5] + 1e-20f;
            #pragma unroll
            for (int k = 0; k < 6; ++k) {
                topk_i[t * 6 + k] = ik[k];
                topk_w[t * 6 + k] = wk[k] / den;
                atomicAdd(&histL[ik[k]], 1);   // LDS atomic — cheap
            }
        }
    }
    __syncthreads();
    if (tid < 64) histPart[tid * 256 + b] = histL[tid];
}

// ---------------------------------------------------------------------------
// Scan (1 block): per-expert 256-wide exclusive scan over gate blocks,
// expert bases, per-(block,expert) offsets boffG[e][b], worklist.
// ---------------------------------------------------------------------------
__global__ __launch_bounds__(256) void k_scan(int* Wi, const int* histPart, int* boffG) {
    __shared__ int hl[16384];
    __shared__ int cntL[64], exclL[64], chxL[65];
    int tid = threadIdx.x, lane = tid & 63, wv = tid >> 6;
    for (int j = tid; j < 16384; j += 256) hl[j] = histPart[j];
    __syncthreads();
    for (int ei = 0; ei < 16; ++ei) {
        int e = wv * 16 + ei;
        int carry = 0;
        for (int r = 0; r < 4; ++r) {
            int v = hl[e * 256 + r * 64 + lane];
            int incl = v;
            #pragma unroll
            for (int off = 1; off < 64; off <<= 1) {
                int ts = __shfl_up(incl, off);
                if (lane >= off) incl += ts;
            }
            hl[e * 256 + r * 64 + lane] = carry + incl - v;
            carry += __shfl(incl, 63);
        }
        if (lane == 0) cntL[e] = carry;
    }
    __syncthreads();
    if (tid == 0) {
        int s = 0, cs = 0;
        for (int e = 0; e < 64; ++e) {
            exclL[e] = s; s += cntL[e];
            chxL[e] = cs; cs += (cntL[e] + 63) >> 6;
        }
        chxL[64] = cs;
        Wi[128] = s;
        Wi[193] = cs + 512;   // nwork
    }
    __syncthreads();
    if (tid < 64) { Wi[tid] = cntL[tid]; Wi[64 + tid] = exclL[tid]; }
    for (int j = tid; j < 16384; j += 256) boffG[j] = hl[j] + exclL[j >> 8];
    if (tid < 64) {
        int e = tid, nc = (cntL[e] + 63) >> 6, bb = chxL[e];
        for (int c = 0; c < nc; ++c) Wi[256 + bb + c] = (e << 16) | c;
    }
    int R = chxL[64];
    for (int j = tid; j < 512; j += 256)
        Wi[256 + R + j] = ((64 + (j >> 8)) << 16) | (j & 255);
}

// ---------------------------------------------------------------------------
// Scatter: block b handles gate block b's 384 (token,expert) entries.
// LDS counters seeded from boffG — LDS atomics only.
// ---------------------------------------------------------------------------
__global__ __launch_bounds__(256) void k_scatter(const int* topk_i, const float* topk_w,
        const int* boffG, int* perm, float* permw) {
    __shared__ int lcur[64];
    int tid = threadIdx.x, b = blockIdx.x;
    if (tid < 64) lcur[tid] = boffG[tid * 256 + b];
    __syncthreads();
    for (int i = tid; i < 384; i += 256) {
        int g = b * 384 + i;
        int e = topk_i[g];
        float w = topk_w[g];
        int p = atomicAdd(&lcur[e], 1);
        perm[p]  = b * 64 + i / 6;
        permw[p] = w;
    }
}

// ---------------------------------------------------------------------------
// Expert MLP: per (expert, 64-token chunk).  4 waves.
// LDS tiles swizzled: byte = row*256 + (colByte ^ ((row&7)<<4))  (16B granular).
// GEMM1: h = silu(x@wgT^T)*(x@wuT^T);  GEMM2 (swapped): y^T = wdT @ h^T, K->96.
// ---------------------------------------------------------------------------
__global__ __launch_bounds__(256) void k_expert(const ushort_t* x, const ushort_t* wgT,
        const ushort_t* wuT, const ushort_t* wdT, const int* Wi, const int* perm,
        const float* permw, float* ybuf) {
    __shared__ char smem[53760];
    char* xl   = smem;
    char* wbuf = smem + 16384;
    char* hl   = smem + 36864;
    int*   tokL = (int*)(smem + 53248);
    float* wtL  = (float*)(smem + 53504);

    if (blockIdx.x >= Wi[193]) return;
    int entry = Wi[256 + blockIdx.x];
    int e = entry >> 16, c = entry & 0xffff;
    int tid = threadIdx.x, lid = tid & 63, wv = tid >> 6;
    int nrows = 64, base = 0;
    if (e < 64) {
        int n = Wi[e]; base = Wi[64 + e];
        nrows = n - c * 64; if (nrows > 64) nrows = 64;
    }

    if (tid < 64) {
        int r = tid, t = 0; float w = 0.f;
        if (r < nrows) {
            if (e < 64) { t = perm[base + c * 64 + r]; w = permw[base + c * 64 + r]; }
            else        { t = c * 64 + r; w = 1.0f; }
        }
        tokL[r] = t; wtL[r] = w;
    }

    // stage x tile (zero-pad invalid rows)
    #pragma unroll
    for (int u = tid; u < 1024; u += 256) {
        int r = u >> 4, ch = u & 15;
        uint4 v = {0u, 0u, 0u, 0u};
        if (r < nrows) {
            int t = (e < 64) ? perm[base + c * 64 + r] : (c * 64 + r);
            v = *(const uint4*)(x + t * 128 + ch * 8);
        }
        *(uint4*)(xl + r * 256 + ((ch * 16) ^ ((r & 7) << 4))) = v;
    }
    // stage wgT (80 rows x 128)
    {
        const ushort_t* wsrc = wgT + e * 10240;
        #pragma unroll
        for (int u = tid; u < 1280; u += 256) {
            int r = u >> 4, ch = u & 15;
            uint4 v = *(const uint4*)(wsrc + r * 128 + ch * 8);
            *(uint4*)(wbuf + r * 256 + ((ch * 16) ^ ((r & 7) << 4))) = v;
        }
    }
    __syncthreads();

    int arow = wv * 16 + (lid & 15);
    int kg = (lid >> 4) * 16;   // lane-group k byte offset
    bf16x8 a[4];
    #pragma unroll
    for (int k = 0; k < 4; ++k)
        a[k] = *(const bf16x8*)(xl + arow * 256 + (((k * 64) + kg) ^ ((arow & 7) << 4)));

    f32x4 accg[5], accu[5];
    #pragma unroll
    for (int mi = 0; mi < 5; ++mi) {
        f32x4 acc = {0.f, 0.f, 0.f, 0.f};
        int brow = mi * 16 + (lid & 15);
        #pragma unroll
        for (int k = 0; k < 4; ++k) {
            bf16x8 b = *(const bf16x8*)(wbuf + brow * 256 + (((k * 64) + kg) ^ ((brow & 7) << 4)));
            acc = __builtin_amdgcn_mfma_f32_16x16x32_bf16(a[k], b, acc, 0, 0, 0);
        }
        accg[mi] = acc;
    }
    __syncthreads();
    // restage with wuT
    {
        const ushort_t* wsrc = wuT + e * 10240;
        #pragma unroll
        for (int u = tid; u < 1280; u += 256) {
            int r = u >> 4, ch = u & 15;
            uint4 v = *(const uint4*)(wsrc + r * 128 + ch * 8);
            *(uint4*)(wbuf + r * 256 + ((ch * 16) ^ ((r & 7) << 4))) = v;
        }
    }
    __syncthreads();
    #pragma unroll
    for (int mi = 0; mi < 5; ++mi) {
        f32x4 acc = {0.f, 0.f, 0.f, 0.f};
        int brow = mi * 16 + (lid & 15);
        #pragma unroll
        for (int k = 0; k < 4; ++k) {
            bf16x8 b = *(const bf16x8*)(wbuf + brow * 256 + (((k * 64) + kg) ^ ((brow & 7) << 4)));
            acc = __builtin_amdgcn_mfma_f32_16x16x32_bf16(a[k], b, acc, 0, 0, 0);
        }
        accu[mi] = acc;
    }

    // h = silu(g) * u -> hl (bf16, swizzled), then zero-pad K columns 80..95
    #pragma unroll
    for (int mi = 0; mi < 5; ++mi) {
        #pragma unroll
        for (int rg = 0; rg < 4; ++rg) {
            float g = accg[mi][rg], uu = accu[mi][rg];
            float h = (g / (1.f + expf(-g))) * uu;
            int row = wv * 16 + (lid >> 4) * 4 + rg;
            int cb = (mi * 16 + (lid & 15)) * 2;
            *(ushort_t*)(hl + row * 256 + (cb ^ ((row & 7) << 4))) = f2bf(h);
        }
    }
    if (tid < 128) {
        int r = tid >> 1, ch = 10 + (tid & 1);
        uint4 z = {0u, 0u, 0u, 0u};
        *(uint4*)(hl + r * 256 + ((ch * 16) ^ ((r & 7) << 4))) = z;
    }
    __syncthreads();

    // down projection in two 64-row halves of wdT
    #pragma unroll
    for (int ph = 0; ph < 2; ++ph) {
        #pragma unroll
        for (int u = tid; u < 768; u += 256) {
            int r = u / 12, ch = u % 12;
            uint4 v = {0u, 0u, 0u, 0u};
            if (ch < 10) v = *(const uint4*)(wdT + (e * 128 + ph * 64 + r) * 80 + ch * 8);
            *(uint4*)(wbuf + r * 256 + ((ch * 16) ^ ((r & 7) << 4))) = v;
        }
        __syncthreads();
        int drow = wv * 16 + (lid & 15);
        bf16x8 ad[3];
        #pragma unroll
        for (int k = 0; k < 3; ++k)
            ad[k] = *(const bf16x8*)(wbuf + drow * 256 + (((k * 64) + kg) ^ ((drow & 7) << 4)));
        #pragma unroll
        for (int tf = 0; tf < 4; ++tf) {
            int brow = tf * 16 + (lid & 15);
            f32x4 acc = {0.f, 0.f, 0.f, 0.f};
            #pragma unroll
            for (int k = 0; k < 3; ++k) {
                bf16x8 b = *(const bf16x8*)(hl + brow * 256 + (((k * 64) + kg) ^ ((brow & 7) << 4)));
                acc = __builtin_amdgcn_mfma_f32_16x16x32_bf16(ad[k], b, acc, 0, 0, 0);
            }
            int rloc = tf * 16 + (lid & 15);
            if (rloc < nrows) {
                int t = tokL[rloc]; float w = wtL[rloc];
                int dbase = ph * 64 + wv * 16 + (lid >> 4) * 4;
                #pragma unroll
                for (int rg = 0; rg < 4; ++rg)
                    atomicAdd(&ybuf[t * 128 + dbase + rg], acc[rg] * w);
            }
        }
        __syncthreads();
    }
}

// ---------------------------------------------------------------------------
__global__ __launch_bounds__(256) void k_final(const float* ybuf, void* out, const int* Wi) {
    int i = blockIdx.x * 256 + threadIdx.x;
    int f32m = Wi[195];
    float4 v = ((const float4*)ybuf)[i];
    if (f32m) {
        ((float4*)out)[i] = v;
    } else {
        ushort4 o;
        o.x = f2bf(v.x); o.y = f2bf(v.y); o.z = f2bf(v.z); o.w = f2bf(v.w);
        ((ushort4*)out)[i] = o;
    }
}

// ---------------------------------------------------------------------------
extern "C" void kernel_launch(void* const* d_in, const int* in_sizes, int n_in,
                              void* d_out, int out_size, void* d_ws, size_t ws_size,
                              hipStream_t stream) {
    (void)in_sizes; (void)n_in; (void)out_size; (void)ws_size;
    const void* x   = d_in[0];
    const void* gw  = d_in[1];
    const void* wg  = d_in[2];
    const void* wu  = d_in[3];
    const void* wd  = d_in[4];
    const void* swg = d_in[5];
    const void* swu = d_in[6];
    const void* swd = d_in[7];

    char* ws = (char*)d_ws;
    int*      Wi     = (int*)d_ws;
    int*      topk_i = (int*)(ws + OFF_TOPKI);
    float*    topk_w = (float*)(ws + OFF_TOPKW);
    int*      perm   = (int*)(ws + OFF_PERM);
    float*    permw  = (float*)(ws + OFF_PERMW);
    float*    ybuf   = (float*)(ws + OFF_YBUF);
    ushort_t* wgT    = (ushort_t*)(ws + OFF_WGT);
    ushort_t* wuT    = (ushort_t*)(ws + OFF_WUT);
    ushort_t* wdT    = (ushort_t*)(ws + OFF_WDT);
    ushort_t* xB     = (ushort_t*)(ws + OFF_XB);
    int*      histP  = (int*)(ws + OFF_HIST);
    int*      boffG  = (int*)(ws + OFF_BOFF);

    hipMemsetAsync(d_ws, 0, 1024, stream);
    hipMemsetAsync(ybuf, 0, 16384 * 128 * 4, stream);

    k_detect<<<1, 64, 0, stream>>>((const ushort_t*)gw, Wi);
    k_prep<<<3 * EALL, 256, 0, stream>>>(wg, wu, wd, swg, swu, swd, wgT, wuT, wdT, Wi);
    k_gate<<<256, 256, 0, stream>>>(x, gw, xB, topk_i, topk_w, histP, Wi);
    k_scan<<<1, 256, 0, stream>>>(Wi, histP, boffG);
    k_scatter<<<256, 256, 0, stream>>>(topk_i, topk_w, boffG, perm, permw);
    k_expert<<<2112, 256, 0, stream>>>(xB, wgT, wuT, wdT, Wi, perm, permw, ybuf);
    k_final<<<2048, 256, 0, stream>>>(ybuf, d_out, Wi);
}

// Round 4
// 204.148 us; speedup vs baseline: 4.3738x; 1.8377x over previous
//
#include <hip/hip_runtime.h>
#include <hip/hip_bf16.h>
#include <math.h>

// ---------------------------------------------------------------------------
// DeepseekMoE: T=16384 tokens, D=128, E=64 experts top-6, M=80, shared MS=160.
// Shared expert folded in as experts 64,65; merged into ONE chunk per 64 tokens.
// R4: no combine atomics — expert writes bf16 partials to dense yperm/ysh,
//     k_final gathers via pos2. Fallback to atomic path if ws too small.
// ---------------------------------------------------------------------------

typedef unsigned short ushort_t;
typedef __attribute__((ext_vector_type(8))) short bf16x8;   // 8 bf16 = 4 VGPR
typedef __attribute__((ext_vector_type(4))) float f32x4;

#define EALL  66

// ---- fast-mode workspace byte offsets ----
#define OFF_TOPKI 16384
#define OFF_TOPKW 409600
#define OFF_PERM  802816
#define OFF_PERMW 1196032
#define OFF_POS2  1589248
#define OFF_YPERM 1982464            // bf16 [98304][128] = 25165824
#define OFF_YSH   27148288           // bf16 [16384][128] = 4194304
#define OFF_WGT   31342592           // bf16 [66][80][128]
#define OFF_WUT   32694272
#define OFF_WDT   34045952           // bf16 [66][128][80]
#define OFF_XB    35397632           // bf16 [16384][128]
#define OFF_HIST  39591936
#define OFF_BOFF  39657472
#define NEED_FAST 39723008
// ---- fallback (compact) offsets: ybuf replaces yperm/ysh ----
#define FOFF_YBUF 1982464            // float[16384*128] = 8388608
#define FOFF_WGT  10371072
#define FOFF_WUT  11722752
#define FOFF_WDT  13074432
#define FOFF_XB   14426112
#define FOFF_HIST 18620416
#define FOFF_BOFF 18685952
// int ws indices: Wi[0..63]=cnt, Wi[64..128]=excl, Wi[193]=nwork,
//   Wi[195]=f32mode, Wi[256..]=worklist (<=2112 entries)

__device__ __forceinline__ float bf2f(ushort_t u) {
    unsigned int x = ((unsigned int)u) << 16;
    float f; __builtin_memcpy(&f, &x, 4); return f;
}
__device__ __forceinline__ ushort_t f2bf(float f) {
    unsigned int x; __builtin_memcpy(&x, &f, 4);
    unsigned int r = (x + 0x7fffu + ((x >> 16) & 1u)) >> 16;   // RNE
    return (ushort_t)r;
}
__device__ __forceinline__ float ldin(const void* p, int i, int f32m) {
    return f32m ? ((const float*)p)[i] : bf2f(((const ushort_t*)p)[i]);
}

// ---------------------------------------------------------------------------
__global__ __launch_bounds__(64) void k_detect(const ushort_t* gw, int* Wi) {
    int lane = threadIdx.x;
    int cnt = 0;
    #pragma unroll
    for (int j = 0; j < 4; ++j) {
        ushort_t u = gw[lane * 4 + j];
        if (((u >> 7) & 0xFF) >= 0x7C) cnt++;
    }
    #pragma unroll
    for (int off = 32; off; off >>= 1) cnt += __shfl_xor(cnt, off);
    if (lane == 0) Wi[195] = (cnt >= 8) ? 1 : 0;
}

// ---------------------------------------------------------------------------
// Prep: wgT/wuT[e][m][d] <- wg[e][d][m];  wdT[e][d][m] <- wd[e][m][d]
// ---------------------------------------------------------------------------
__global__ __launch_bounds__(256) void k_prep(const void* wg, const void* wu,
        const void* wd, const void* swg, const void* swu, const void* swd,
        ushort_t* wgT, ushort_t* wuT, ushort_t* wdT, const int* Wi) {
    __shared__ float lds[128 * 81];
    int bid = blockIdx.x, tid = threadIdx.x;
    int mat = bid / EALL, e = bid % EALL;
    int f32m = Wi[195];
    if (mat < 2) {
        const void* src  = (mat == 0) ? wg  : wu;
        const void* ssrc = (mat == 0) ? swg : swu;
        for (int i = tid; i < 10240; i += 256) {
            int d = i / 80, m = i % 80;
            float v = (e < 64) ? ldin(src, e * 10240 + i, f32m)
                               : ldin(ssrc, d * 160 + (e - 64) * 80 + m, f32m);
            lds[d * 81 + m] = v;
        }
        __syncthreads();
        ushort_t* dst = ((mat == 0) ? wgT : wuT) + e * 10240;
        for (int o = tid; o < 10240; o += 256) {
            int m = o >> 7, d = o & 127;
            dst[o] = f2bf(lds[d * 81 + m]);
        }
    } else {
        for (int i = tid; i < 10240; i += 256) {
            float v = (e < 64) ? ldin(wd, e * 10240 + i, f32m)
                               : ldin(swd, (e - 64) * 10240 + i, f32m);
            int m = i >> 7, d = i & 127;
            lds[m * 129 + d] = v;
        }
        __syncthreads();
        ushort_t* dst = wdT + e * 10240;
        for (int o = tid; o < 10240; o += 256) {
            int d = o / 80, m = o % 80;
            dst[o] = f2bf(lds[m * 129 + d]);
        }
    }
}

// ---------------------------------------------------------------------------
// Gating: 256 blocks x 64 tokens; f32 dot; softmax + top-6 + renorm.
// Per-block LDS histogram -> histPart. Emits xB (bf16 x) as side product.
// ---------------------------------------------------------------------------
__global__ __launch_bounds__(256) void k_gate(const void* x, const void* gw,
        ushort_t* xB, int* topk_i, float* topk_w, int* histPart, const int* Wi) {
    __shared__ float gwl[64 * 130];
    __shared__ float xl[4][128];
    __shared__ int histL[64];
    int tid = threadIdx.x, b = blockIdx.x;
    int f32m = Wi[195];
    for (int i = tid; i < 8192; i += 256)
        gwl[(i >> 7) * 130 + (i & 127)] = ldin(gw, i, f32m);
    if (tid < 64) histL[tid] = 0;
    __syncthreads();
    int wv = tid >> 6, lane = tid & 63;
    for (int q = 0; q < 16; ++q) {
        int t = b * 64 + wv * 16 + q;
        float xv0, xv1;
        if (f32m) {
            float2 v = ((const float2*)((const float*)x + t * 128))[lane];
            xv0 = v.x; xv1 = v.y;
        } else {
            unsigned int pr = *(const unsigned int*)((const ushort_t*)x + t * 128 + lane * 2);
            xv0 = bf2f((ushort_t)(pr & 0xffffu));
            xv1 = bf2f((ushort_t)(pr >> 16));
        }
        float2 xw; xw.x = xv0; xw.y = xv1;
        *(float2*)&xl[wv][lane * 2] = xw;
        unsigned int packed = (unsigned int)f2bf(xv0) | ((unsigned int)f2bf(xv1) << 16);
        *(unsigned int*)(xB + t * 128 + lane * 2) = packed;
        float acc = 0.f;
        #pragma unroll
        for (int d2 = 0; d2 < 64; ++d2) {
            float2 xv = *(const float2*)&xl[wv][d2 * 2];
            float2 gv = *(const float2*)&gwl[lane * 130 + d2 * 2];
            acc = fmaf(xv.x, gv.x, acc);
            acc = fmaf(xv.y, gv.y, acc);
        }
        float mx = acc;
        #pragma unroll
        for (int off = 32; off; off >>= 1) mx = fmaxf(mx, __shfl_xor(mx, off));
        float p = expf(acc - mx);
        float sm = p;
        #pragma unroll
        for (int off = 32; off; off >>= 1) sm += __shfl_xor(sm, off);
        float sc = p / sm;
        float cur = sc;
        float wk[6]; int ik[6];
        #pragma unroll
        for (int k = 0; k < 6; ++k) {
            float bv = cur; int bi = lane;
            #pragma unroll
            for (int off = 1; off < 64; off <<= 1) {
                float ov = __shfl_xor(bv, off); int oi = __shfl_xor(bi, off);
                if (ov > bv || (ov == bv && oi < bi)) { bv = ov; bi = oi; }
            }
            wk[k] = bv; ik[k] = bi;
            if (lane == bi) cur = -INFINITY;
        }
        if (lane == 0) {
            float den = wk[0] + wk[1] + wk[2] + wk[3] + wk[4] + wk[5] + 1e-20f;
            #pragma unroll
            for (int k = 0; k < 6; ++k) {
                topk_i[t * 6 + k] = ik[k];
                topk_w[t * 6 + k] = wk[k] / den;
                atomicAdd(&histL[ik[k]], 1);
            }
        }
    }
    __syncthreads();
    if (tid < 64) histPart[tid * 256 + b] = histL[tid];
}

// ---------------------------------------------------------------------------
// Scan (1 block): per-expert scan over gate blocks, bases, worklist.
// Worklist: routed chunks (e<64) + 256 merged shared chunks (e==64).
// ---------------------------------------------------------------------------
__global__ __launch_bounds__(256) void k_scan(int* Wi, const int* histPart, int* boffG) {
    __shared__ int hl[16384];
    __shared__ int cntL[64], exclL[64], chxL[65];
    int tid = threadIdx.x, lane = tid & 63, wv = tid >> 6;
    for (int j = tid; j < 16384; j += 256) hl[j] = histPart[j];
    __syncthreads();
    for (int ei = 0; ei < 16; ++ei) {
        int e = wv * 16 + ei;
        int carry = 0;
        for (int r = 0; r < 4; ++r) {
            int v = hl[e * 256 + r * 64 + lane];
            int incl = v;
            #pragma unroll
            for (int off = 1; off < 64; off <<= 1) {
                int ts = __shfl_up(incl, off);
                if (lane >= off) incl += ts;
            }
            hl[e * 256 + r * 64 + lane] = carry + incl - v;
            carry += __shfl(incl, 63);
        }
        if (lane == 0) cntL[e] = carry;
    }
    __syncthreads();
    if (tid == 0) {
        int s = 0, cs = 0;
        for (int e = 0; e < 64; ++e) {
            exclL[e] = s; s += cntL[e];
            chxL[e] = cs; cs += (cntL[e] + 63) >> 6;
        }
        chxL[64] = cs;
        Wi[128] = s;
        Wi[193] = cs + 256;   // nwork (256 merged shared chunks)
    }
    __syncthreads();
    if (tid < 64) { Wi[tid] = cntL[tid]; Wi[64 + tid] = exclL[tid]; }
    for (int j = tid; j < 16384; j += 256) boffG[j] = hl[j] + exclL[j >> 8];
    if (tid < 64) {
        int e = tid, nc = (cntL[e] + 63) >> 6, bb = chxL[e];
        for (int c = 0; c < nc; ++c) Wi[256 + bb + c] = (e << 16) | c;
    }
    int R = chxL[64];
    for (int j = tid; j < 256; j += 256)
        Wi[256 + R + j] = (64 << 16) | j;
}

// ---------------------------------------------------------------------------
// Scatter: LDS counters seeded from boffG; also records pos2 for the gather.
// ---------------------------------------------------------------------------
__global__ __launch_bounds__(256) void k_scatter(const int* topk_i, const float* topk_w,
        const int* boffG, int* perm, float* permw, int* pos2) {
    __shared__ int lcur[64];
    int tid = threadIdx.x, b = blockIdx.x;
    if (tid < 64) lcur[tid] = boffG[tid * 256 + b];
    __syncthreads();
    for (int i = tid; i < 384; i += 256) {
        int g = b * 384 + i;
        int e = topk_i[g];
        float w = topk_w[g];
        int p = atomicAdd(&lcur[e], 1);
        perm[p]  = b * 64 + i / 6;
        permw[p] = w;
        pos2[g]  = p;
    }
}

// ---------------------------------------------------------------------------
// Expert MLP. Routed chunk: 1 expert x 64 tokens. Shared chunk (e==64):
// both halves (experts 64,65) accumulated in registers.
// LDS: xl 16K | wbA 20K | wbB 20K | hl 16K | tok/wt 512B = 72.5 KB (2 blk/CU).
// Swizzle: byte = row*256 + (colByte ^ ((row&7)<<4)).
// FAST=1: weighted bf16 partials -> yperm/ysh (no atomics).
// FAST=0: fp32 atomicAdd -> ybuf.
// ---------------------------------------------------------------------------
template<int FAST>
__global__ __launch_bounds__(256) void k_expert(const ushort_t* x, const ushort_t* wgT,
        const ushort_t* wuT, const ushort_t* wdT, const int* Wi, const int* perm,
        const float* permw, ushort_t* yperm, ushort_t* ysh, float* ybuf) {
    __shared__ char smem[74240];
    char* xl   = smem;                    // 64 x 256B
    char* wbA  = smem + 16384;            // 80 x 256B
    char* wbB  = smem + 36864;            // 80 x 256B
    char* hl   = smem + 57344;            // 64 x 256B
    int*   tokL = (int*)(smem + 73728);
    float* wtL  = (float*)(smem + 73984);

    if (blockIdx.x >= Wi[193]) return;
    int entry = Wi[256 + blockIdx.x];
    int e = entry >> 16, c = entry & 0xffff;
    int tid = threadIdx.x, lid = tid & 63, wv = tid >> 6;
    int nrows = 64, base = 0;
    if (e < 64) {
        int n = Wi[e]; base = Wi[64 + e];
        nrows = n - c * 64; if (nrows > 64) nrows = 64;
    }

    if (tid < 64) {
        int r = tid, t = 0; float w = 0.f;
        if (r < nrows) {
            if (e < 64) { t = perm[base + c * 64 + r]; w = permw[base + c * 64 + r]; }
            else        { t = c * 64 + r; w = 1.0f; }
        }
        tokL[r] = t; wtL[r] = w;
    }

    // stage x tile (zero-pad invalid rows)
    #pragma unroll
    for (int u = tid; u < 1024; u += 256) {
        int r = u >> 4, ch = u & 15;
        uint4 v = {0u, 0u, 0u, 0u};
        if (r < nrows) {
            int t = (e < 64) ? perm[base + c * 64 + r] : (c * 64 + r);
            v = *(const uint4*)(x + t * 128 + ch * 8);
        }
        *(uint4*)(xl + r * 256 + ((ch * 16) ^ ((r & 7) << 4))) = v;
    }

    int kg = (lid >> 4) * 16;
    int arow = wv * 16 + (lid & 15);
    int nsub = (e < 64) ? 1 : 2;

    f32x4 accd0[4], accd1[4];
    #pragma unroll
    for (int tf = 0; tf < 4; ++tf) {
        accd0[tf] = (f32x4){0.f, 0.f, 0.f, 0.f};
        accd1[tf] = (f32x4){0.f, 0.f, 0.f, 0.f};
    }

    for (int sub = 0; sub < nsub; ++sub) {
        int ee = (e < 64) ? e : (64 + sub);
        // stage wgT -> wbA, wuT -> wbB  (concurrent)
        {
            const ushort_t* gsrc = wgT + ee * 10240;
            const ushort_t* usrc = wuT + ee * 10240;
            #pragma unroll
            for (int u = tid; u < 2560; u += 256) {
                int half = u >> 11;             // 0: wg, 1: wu
                int uu = u & 2047;
                int r = uu >> 4, ch = uu & 15;
                const ushort_t* src = half ? usrc : gsrc;
                // 2048 covers 128 rows of 16ch -> need 80 rows only: u layout below
                (void)src; (void)r; (void)ch;
            }
            // 80 rows x 16 ch = 1280 per matrix; loop 2560 with explicit split
            for (int u = tid; u < 2560; u += 256) {
                int half = (u >= 1280) ? 1 : 0;
                int uu = half ? (u - 1280) : u;
                int r = uu >> 4, ch = uu & 15;
                uint4 v = *(const uint4*)((half ? usrc : gsrc) + r * 128 + ch * 8);
                char* wb = half ? wbB : wbA;
                *(uint4*)(wb + r * 256 + ((ch * 16) ^ ((r & 7) << 4))) = v;
            }
        }
        __syncthreads();

        bf16x8 a[4];
        #pragma unroll
        for (int k = 0; k < 4; ++k)
            a[k] = *(const bf16x8*)(xl + arow * 256 + (((k * 64) + kg) ^ ((arow & 7) << 4)));

        f32x4 accg[5], accu[5];
        #pragma unroll
        for (int mi = 0; mi < 5; ++mi) {
            f32x4 ag = {0.f, 0.f, 0.f, 0.f};
            f32x4 au = {0.f, 0.f, 0.f, 0.f};
            int brow = mi * 16 + (lid & 15);
            #pragma unroll
            for (int k = 0; k < 4; ++k) {
                int bo = ((k * 64) + kg) ^ ((brow & 7) << 4);
                bf16x8 bg = *(const bf16x8*)(wbA + brow * 256 + bo);
                bf16x8 bu = *(const bf16x8*)(wbB + brow * 256 + bo);
                ag = __builtin_amdgcn_mfma_f32_16x16x32_bf16(a[k], bg, ag, 0, 0, 0);
                au = __builtin_amdgcn_mfma_f32_16x16x32_bf16(a[k], bu, au, 0, 0, 0);
            }
            accg[mi] = ag; accu[mi] = au;
        }

        // h = silu(g)*u -> hl
        #pragma unroll
        for (int mi = 0; mi < 5; ++mi) {
            #pragma unroll
            for (int rg = 0; rg < 4; ++rg) {
                float g = accg[mi][rg], uu2 = accu[mi][rg];
                float h = (g / (1.f + expf(-g))) * uu2;
                int row = wv * 16 + (lid >> 4) * 4 + rg;
                int cb = (mi * 16 + (lid & 15)) * 2;
                *(ushort_t*)(hl + row * 256 + (cb ^ ((row & 7) << 4))) = f2bf(h);
            }
        }
        if (sub == 0 && tid < 128) {     // zero-pad K cols 80..95 once
            int r = tid >> 1, ch = 10 + (tid & 1);
            uint4 z = {0u, 0u, 0u, 0u};
            *(uint4*)(hl + r * 256 + ((ch * 16) ^ ((r & 7) << 4))) = z;
        }
        __syncthreads();   // all GEMM1 reads done; hl complete

        // stage wd: rows 0..63 -> wbA, rows 64..127 -> wbB
        {
            const ushort_t* dsrc = wdT + ee * 10240;
            for (int u = tid; u < 1536; u += 256) {
                int half = (u >= 768) ? 1 : 0;
                int uu = half ? (u - 768) : u;
                int r = uu / 12, ch = uu % 12;
                uint4 v = {0u, 0u, 0u, 0u};
                if (ch < 10) v = *(const uint4*)(dsrc + (half * 64 + r) * 80 + ch * 8);
                char* wb = half ? wbB : wbA;
                *(uint4*)(wb + r * 256 + ((ch * 16) ^ ((r & 7) << 4))) = v;
            }
        }
        __syncthreads();

        // GEMM2: accumulate both halves into persistent accd
        int drow = wv * 16 + (lid & 15);
        {
            bf16x8 ad[3];
            #pragma unroll
            for (int k = 0; k < 3; ++k)
                ad[k] = *(const bf16x8*)(wbA + drow * 256 + (((k * 64) + kg) ^ ((drow & 7) << 4)));
            #pragma unroll
            for (int tf = 0; tf < 4; ++tf) {
                int brow = tf * 16 + (lid & 15);
                f32x4 acc = accd0[tf];
                #pragma unroll
                for (int k = 0; k < 3; ++k) {
                    bf16x8 b = *(const bf16x8*)(hl + brow * 256 + (((k * 64) + kg) ^ ((brow & 7) << 4)));
                    acc = __builtin_amdgcn_mfma_f32_16x16x32_bf16(ad[k], b, acc, 0, 0, 0);
                }
                accd0[tf] = acc;
            }
        }
        {
            bf16x8 ad[3];
            #pragma unroll
            for (int k = 0; k < 3; ++k)
                ad[k] = *(const bf16x8*)(wbB + drow * 256 + (((k * 64) + kg) ^ ((drow & 7) << 4)));
            #pragma unroll
            for (int tf = 0; tf < 4; ++tf) {
                int brow = tf * 16 + (lid & 15);
                f32x4 acc = accd1[tf];
                #pragma unroll
                for (int k = 0; k < 3; ++k) {
                    bf16x8 b = *(const bf16x8*)(hl + brow * 256 + (((k * 64) + kg) ^ ((brow & 7) << 4)));
                    acc = __builtin_amdgcn_mfma_f32_16x16x32_bf16(ad[k], b, acc, 0, 0, 0);
                }
                accd1[tf] = acc;
            }
        }
        if (sub + 1 < nsub) __syncthreads();   // before overwriting wbA/wbB/hl
    }

    // epilogue
    #pragma unroll
    for (int tf = 0; tf < 4; ++tf) {
        int rloc = tf * 16 + (lid & 15);
        if (rloc >= nrows) continue;
        float w = wtL[rloc];
        int dbase = wv * 16 + (lid >> 4) * 4;
        if (FAST) {
            ushort_t* dst = (e < 64)
                ? (yperm + (size_t)(base + c * 64 + rloc) * 128)
                : (ysh   + (size_t)(c * 64 + rloc) * 128);
            ushort_t o0[4], o1[4];
            #pragma unroll
            for (int rg = 0; rg < 4; ++rg) {
                o0[rg] = f2bf(accd0[tf][rg] * w);
                o1[rg] = f2bf(accd1[tf][rg] * w);
            }
            *(uint2*)(dst + dbase)      = *(const uint2*)o0;
            *(uint2*)(dst + 64 + dbase) = *(const uint2*)o1;
        } else {
            int t = tokL[rloc];
            #pragma unroll
            for (int rg = 0; rg < 4; ++rg) {
                atomicAdd(&ybuf[t * 128 + dbase + rg],      accd0[tf][rg] * w);
                atomicAdd(&ybuf[t * 128 + 64 + dbase + rg], accd1[tf][rg] * w);
            }
        }
    }
}

// ---------------------------------------------------------------------------
// Final gather: out[t] = sum_k yperm[pos2[t*6+k]] + ysh[t].
// 1024 blocks x 256 threads; thread owns 8 cols of one token.
// ---------------------------------------------------------------------------
__global__ __launch_bounds__(256) void k_final_gather(const ushort_t* yperm,
        const ushort_t* ysh, const int* pos2, void* out, const int* Wi) {
    int idx = blockIdx.x * 256 + threadIdx.x;
    int t = idx >> 4, cg = (idx & 15) * 8;
    int f32m = Wi[195];
    float acc[8];
    {
        uint4 v = *(const uint4*)(ysh + (size_t)t * 128 + cg);
        const ushort_t* u = (const ushort_t*)&v;
        #pragma unroll
        for (int j = 0; j < 8; ++j) acc[j] = bf2f(u[j]);
    }
    const int* pp = pos2 + t * 6;
    #pragma unroll
    for (int k = 0; k < 6; ++k) {
        int p = pp[k];
        uint4 v = *(const uint4*)(yperm + (size_t)p * 128 + cg);
        const ushort_t* u = (const ushort_t*)&v;
        #pragma unroll
        for (int j = 0; j < 8; ++j) acc[j] += bf2f(u[j]);
    }
    if (f32m) {
        float4 o0 = {acc[0], acc[1], acc[2], acc[3]};
        float4 o1 = {acc[4], acc[5], acc[6], acc[7]};
        float* op = (float*)out + (size_t)t * 128 + cg;
        *(float4*)op = o0; *(float4*)(op + 4) = o1;
    } else {
        ushort_t o[8];
        #pragma unroll
        for (int j = 0; j < 8; ++j) o[j] = f2bf(acc[j]);
        *(uint4*)((ushort_t*)out + (size_t)t * 128 + cg) = *(const uint4*)o;
    }
}

// fallback: read fp32 ybuf
__global__ __launch_bounds__(256) void k_final_ybuf(const float* ybuf, void* out, const int* Wi) {
    int i = blockIdx.x * 256 + threadIdx.x;
    int f32m = Wi[195];
    float4 v = ((const float4*)ybuf)[i];
    if (f32m) {
        ((float4*)out)[i] = v;
    } else {
        ushort4 o;
        o.x = f2bf(v.x); o.y = f2bf(v.y); o.z = f2bf(v.z); o.w = f2bf(v.w);
        ((ushort4*)out)[i] = o;
    }
}

// ---------------------------------------------------------------------------
extern "C" void kernel_launch(void* const* d_in, const int* in_sizes, int n_in,
                              void* d_out, int out_size, void* d_ws, size_t ws_size,
                              hipStream_t stream) {
    (void)in_sizes; (void)n_in; (void)out_size;
    const void* x   = d_in[0];
    const void* gw  = d_in[1];
    const void* wg  = d_in[2];
    const void* wu  = d_in[3];
    const void* wd  = d_in[4];
    const void* swg = d_in[5];
    const void* swu = d_in[6];
    const void* swd = d_in[7];

    char* ws = (char*)d_ws;
    int fast = (ws_size >= (size_t)NEED_FAST) ? 1 : 0;

    int*      Wi     = (int*)d_ws;
    int*      topk_i = (int*)(ws + OFF_TOPKI);
    float*    topk_w = (float*)(ws + OFF_TOPKW);
    int*      perm   = (int*)(ws + OFF_PERM);
    float*    permw  = (float*)(ws + OFF_PERMW);
    int*      pos2   = (int*)(ws + OFF_POS2);

    ushort_t* yperm = (ushort_t*)(ws + OFF_YPERM);
    ushort_t* ysh   = (ushort_t*)(ws + OFF_YSH);
    float*    ybuf  = (float*)(ws + FOFF_YBUF);
    ushort_t* wgT   = (ushort_t*)(ws + (fast ? OFF_WGT  : FOFF_WGT));
    ushort_t* wuT   = (ushort_t*)(ws + (fast ? OFF_WUT  : FOFF_WUT));
    ushort_t* wdT   = (ushort_t*)(ws + (fast ? OFF_WDT  : FOFF_WDT));
    ushort_t* xB    = (ushort_t*)(ws + (fast ? OFF_XB   : FOFF_XB));
    int*      histP = (int*)(ws + (fast ? OFF_HIST : FOFF_HIST));
    int*      boffG = (int*)(ws + (fast ? OFF_BOFF : FOFF_BOFF));

    hipMemsetAsync(d_ws, 0, 1024, stream);
    if (!fast) hipMemsetAsync(ybuf, 0, 16384 * 128 * 4, stream);

    k_detect<<<1, 64, 0, stream>>>((const ushort_t*)gw, Wi);
    k_prep<<<3 * EALL, 256, 0, stream>>>(wg, wu, wd, swg, swu, swd, wgT, wuT, wdT, Wi);
    k_gate<<<256, 256, 0, stream>>>(x, gw, xB, topk_i, topk_w, histP, Wi);
    k_scan<<<1, 256, 0, stream>>>(Wi, histP, boffG);
    k_scatter<<<256, 256, 0, stream>>>(topk_i, topk_w, boffG, perm, permw, pos2);
    if (fast) {
        k_expert<1><<<1856, 256, 0, stream>>>(xB, wgT, wuT, wdT, Wi, perm, permw, yperm, ysh, ybuf);
        k_final_gather<<<1024, 256, 0, stream>>>(yperm, ysh, pos2, d_out, Wi);
    } else {
        k_expert<0><<<1856, 256, 0, stream>>>(xB, wgT, wuT, wdT, Wi, perm, permw, yperm, ysh, ybuf);
        k_final_ybuf<<<2048, 256, 0, stream>>>(ybuf, d_out, Wi);
    }
}

// Round 5
// 146.796 us; speedup vs baseline: 6.0826x; 1.3907x over previous
//
#include <hip/hip_runtime.h>
#include <hip/hip_bf16.h>
#include <math.h>

// ---------------------------------------------------------------------------
// DeepseekMoE: T=16384 tokens, D=128, E=64 experts top-6, M=80, shared MS=160.
// Shared expert folded in as experts 64,65; merged into ONE chunk per 64 tokens.
// R5: k_gate 1024-thr blocks (occupancy 11->50%); k_expert loads A/B fragments
//     direct from global (weights L2-resident), LDS only for h; 1 barrier/chunk.
// ---------------------------------------------------------------------------

typedef unsigned short ushort_t;
typedef __attribute__((ext_vector_type(8))) short bf16x8;   // 8 bf16 = 4 VGPR
typedef __attribute__((ext_vector_type(4))) float f32x4;

#define EALL  66

// ---- fast-mode workspace byte offsets ----
#define OFF_TOPKI 16384
#define OFF_TOPKW 802816
#define OFF_PERM  1196032
#define OFF_PERMW 1589248
#define OFF_POS2  1982464
#define OFF_YPERM 2375680            // bf16 [98304][128] = 25165824
#define OFF_YSH   27541504           // bf16 [16384][128] = 4194304
#define OFF_WGT   31735808           // bf16 [66][80][128] = 1351680
#define OFF_WUT   33087488
#define OFF_WDP   34439168           // bf16 [66][128][96] = 1622016 (zero-padded)
#define OFF_XB    36061184           // bf16 [16384][128] = 4194304
#define OFF_HIST  40255488
#define OFF_BOFF  40321024
#define NEED_FAST 40386560
// ---- fallback (compact) offsets: ybuf replaces yperm/ysh ----
#define FOFF_YBUF 2375680            // float[16384*128] = 8388608
#define FOFF_WGT  10764288
#define FOFF_WUT  12115968
#define FOFF_WDP  13467648
#define FOFF_XB   15089664
#define FOFF_HIST 19283968
#define FOFF_BOFF 19349504
// int ws indices: Wi[0..63]=cnt, Wi[64..128]=excl, Wi[193]=nwork,
//   Wi[195]=f32mode, Wi[256..]=worklist (<=2112 entries)

__device__ __forceinline__ float bf2f(ushort_t u) {
    unsigned int x = ((unsigned int)u) << 16;
    float f; __builtin_memcpy(&f, &x, 4); return f;
}
__device__ __forceinline__ ushort_t f2bf(float f) {
    unsigned int x; __builtin_memcpy(&x, &f, 4);
    unsigned int r = (x + 0x7fffu + ((x >> 16) & 1u)) >> 16;   // RNE
    return (ushort_t)r;
}
__device__ __forceinline__ float ldin(const void* p, int i, int f32m) {
    return f32m ? ((const float*)p)[i] : bf2f(((const ushort_t*)p)[i]);
}

// ---------------------------------------------------------------------------
__global__ __launch_bounds__(64) void k_detect(const ushort_t* gw, int* Wi) {
    int lane = threadIdx.x;
    int cnt = 0;
    #pragma unroll
    for (int j = 0; j < 4; ++j) {
        ushort_t u = gw[lane * 4 + j];
        if (((u >> 7) & 0xFF) >= 0x7C) cnt++;
    }
    #pragma unroll
    for (int off = 32; off; off >>= 1) cnt += __shfl_xor(cnt, off);
    if (lane == 0) Wi[195] = (cnt >= 8) ? 1 : 0;
}

// ---------------------------------------------------------------------------
// Prep: wgT/wuT[e][m][d] <- wg[e][d][m];  wdP[e][d][m(96,pad0)] <- wd[e][m][d]
// ---------------------------------------------------------------------------
__global__ __launch_bounds__(256) void k_prep(const void* wg, const void* wu,
        const void* wd, const void* swg, const void* swu, const void* swd,
        ushort_t* wgT, ushort_t* wuT, ushort_t* wdP, const int* Wi) {
    __shared__ float lds[128 * 81];
    int bid = blockIdx.x, tid = threadIdx.x;
    int mat = bid / EALL, e = bid % EALL;
    int f32m = Wi[195];
    if (mat < 2) {
        const void* src  = (mat == 0) ? wg  : wu;
        const void* ssrc = (mat == 0) ? swg : swu;
        for (int i = tid; i < 10240; i += 256) {
            int d = i / 80, m = i % 80;
            float v = (e < 64) ? ldin(src, e * 10240 + i, f32m)
                               : ldin(ssrc, d * 160 + (e - 64) * 80 + m, f32m);
            lds[d * 81 + m] = v;
        }
        __syncthreads();
        ushort_t* dst = ((mat == 0) ? wgT : wuT) + e * 10240;
        for (int o = tid; o < 10240; o += 256) {
            int m = o >> 7, d = o & 127;
            dst[o] = f2bf(lds[d * 81 + m]);
        }
    } else {
        for (int i = tid; i < 10240; i += 256) {
            float v = (e < 64) ? ldin(wd, e * 10240 + i, f32m)
                               : ldin(swd, (e - 64) * 10240 + i, f32m);
            int m = i >> 7, d = i & 127;
            lds[m * 129 + d] = v;
        }
        __syncthreads();
        ushort_t* dst = wdP + e * 12288;
        for (int o = tid; o < 12288; o += 256) {
            int d = o / 96, m = o % 96;
            dst[o] = (m < 80) ? f2bf(lds[m * 129 + d]) : (ushort_t)0;
        }
    }
}

// ---------------------------------------------------------------------------
// Gating: 256 blocks x 1024 threads (16 waves) x 4 tokens/wave = 64 tok/block.
// f32 dot (matches reference top-k), softmax + top-6 + renorm.
// Per-block LDS histogram -> histPart. Emits xB (bf16 x) as side product.
// ---------------------------------------------------------------------------
__global__ __launch_bounds__(1024) void k_gate(const void* x, const void* gw,
        ushort_t* xB, int* topk_i, float* topk_w, int* histPart, const int* Wi) {
    __shared__ float gwl[64 * 130];        // 33280 B
    __shared__ float xl[16][128];          // 8192 B
    __shared__ int histL[64];
    int tid = threadIdx.x, b = blockIdx.x;
    int f32m = Wi[195];
    for (int i = tid; i < 8192; i += 1024)
        gwl[(i >> 7) * 130 + (i & 127)] = ldin(gw, i, f32m);
    if (tid < 64) histL[tid] = 0;
    __syncthreads();
    int wv = tid >> 6, lane = tid & 63;
    for (int q = 0; q < 4; ++q) {
        int t = b * 64 + wv * 4 + q;
        float xv0, xv1;
        if (f32m) {
            float2 v = ((const float2*)((const float*)x + t * 128))[lane];
            xv0 = v.x; xv1 = v.y;
        } else {
            unsigned int pr = *(const unsigned int*)((const ushort_t*)x + t * 128 + lane * 2);
            xv0 = bf2f((ushort_t)(pr & 0xffffu));
            xv1 = bf2f((ushort_t)(pr >> 16));
        }
        float2 xw; xw.x = xv0; xw.y = xv1;
        *(float2*)&xl[wv][lane * 2] = xw;
        unsigned int packed = (unsigned int)f2bf(xv0) | ((unsigned int)f2bf(xv1) << 16);
        *(unsigned int*)(xB + t * 128 + lane * 2) = packed;
        float acc = 0.f;
        #pragma unroll
        for (int d2 = 0; d2 < 64; ++d2) {
            float2 xv = *(const float2*)&xl[wv][d2 * 2];
            float2 gv = *(const float2*)&gwl[lane * 130 + d2 * 2];
            acc = fmaf(xv.x, gv.x, acc);
            acc = fmaf(xv.y, gv.y, acc);
        }
        float mx = acc;
        #pragma unroll
        for (int off = 32; off; off >>= 1) mx = fmaxf(mx, __shfl_xor(mx, off));
        float p = expf(acc - mx);
        float sm = p;
        #pragma unroll
        for (int off = 32; off; off >>= 1) sm += __shfl_xor(sm, off);
        float sc = p / sm;
        float cur = sc;
        float wk[6]; int ik[6];
        #pragma unroll
        for (int k = 0; k < 6; ++k) {
            float bv = cur; int bi = lane;
            #pragma unroll
            for (int off = 1; off < 64; off <<= 1) {
                float ov = __shfl_xor(bv, off); int oi = __shfl_xor(bi, off);
                if (ov > bv || (ov == bv && oi < bi)) { bv = ov; bi = oi; }
            }
            wk[k] = bv; ik[k] = bi;
            if (lane == bi) cur = -INFINITY;
        }
        if (lane == 0) {
            float den = wk[0] + wk[1] + wk[2] + wk[3] + wk[4] + wk[5] + 1e-20f;
            #pragma unroll
            for (int k = 0; k < 6; ++k) {
                topk_i[t * 6 + k] = ik[k];
                topk_w[t * 6 + k] = wk[k] / den;
                atomicAdd(&histL[ik[k]], 1);
            }
        }
    }
    __syncthreads();
    if (tid < 64) histPart[tid * 256 + b] = histL[tid];
}

// ---------------------------------------------------------------------------
// Scan (1 block): per-expert scan over gate blocks, bases, worklist.
// ---------------------------------------------------------------------------
__global__ __launch_bounds__(256) void k_scan(int* Wi, const int* histPart, int* boffG) {
    __shared__ int hl[16384];
    __shared__ int cntL[64], exclL[64], chxL[65];
    int tid = threadIdx.x, lane = tid & 63, wv = tid >> 6;
    for (int j = tid; j < 16384; j += 256) hl[j] = histPart[j];
    __syncthreads();
    for (int ei = 0; ei < 16; ++ei) {
        int e = wv * 16 + ei;
        int carry = 0;
        for (int r = 0; r < 4; ++r) {
            int v = hl[e * 256 + r * 64 + lane];
            int incl = v;
            #pragma unroll
            for (int off = 1; off < 64; off <<= 1) {
                int ts = __shfl_up(incl, off);
                if (lane >= off) incl += ts;
            }
            hl[e * 256 + r * 64 + lane] = carry + incl - v;
            carry += __shfl(incl, 63);
        }
        if (lane == 0) cntL[e] = carry;
    }
    __syncthreads();
    if (tid == 0) {
        int s = 0, cs = 0;
        for (int e = 0; e < 64; ++e) {
            exclL[e] = s; s += cntL[e];
            chxL[e] = cs; cs += (cntL[e] + 63) >> 6;
        }
        chxL[64] = cs;
        Wi[128] = s;
        Wi[193] = cs + 256;   // nwork (256 merged shared chunks)
    }
    __syncthreads();
    if (tid < 64) { Wi[tid] = cntL[tid]; Wi[64 + tid] = exclL[tid]; }
    for (int j = tid; j < 16384; j += 256) boffG[j] = hl[j] + exclL[j >> 8];
    if (tid < 64) {
        int e = tid, nc = (cntL[e] + 63) >> 6, bb = chxL[e];
        for (int c = 0; c < nc; ++c) Wi[256 + bb + c] = (e << 16) | c;
    }
    int R = chxL[64];
    for (int j = tid; j < 256; j += 256)
        Wi[256 + R + j] = (64 << 16) | j;
}

// ---------------------------------------------------------------------------
// Scatter: LDS counters seeded from boffG; records pos2 for the gather.
// ---------------------------------------------------------------------------
__global__ __launch_bounds__(256) void k_scatter(const int* topk_i, const float* topk_w,
        const int* boffG, int* perm, float* permw, int* pos2) {
    __shared__ int lcur[64];
    int tid = threadIdx.x, b = blockIdx.x;
    if (tid < 64) lcur[tid] = boffG[tid * 256 + b];
    __syncthreads();
    for (int i = tid; i < 384; i += 256) {
        int g = b * 384 + i;
        int e = topk_i[g];
        float w = topk_w[g];
        int p = atomicAdd(&lcur[e], 1);
        perm[p]  = b * 64 + i / 6;
        permw[p] = w;
        pos2[g]  = p;
    }
}

// ---------------------------------------------------------------------------
// Expert MLP. Routed chunk: 1 expert x 64 tokens. Shared chunk (e==64):
// halves 64,65 accumulated in registers. A/B fragments DIRECT FROM GLOBAL
// (weights L2-resident, perfectly aligned 16-B per lane); LDS only for h.
// hl swizzle: byte = row*256 + (colByte ^ ((row&7)<<4)).
// ---------------------------------------------------------------------------
template<int FAST>
__global__ __launch_bounds__(256) void k_expert(const ushort_t* x, const ushort_t* wgT,
        const ushort_t* wuT, const ushort_t* wdP, const int* Wi, const int* perm,
        const float* permw, ushort_t* yperm, ushort_t* ysh, float* ybuf) {
    __shared__ __align__(16) char hl[16384];   // 64 rows x 256B (K padded to 96)

    if (blockIdx.x >= Wi[193]) return;
    int entry = Wi[256 + blockIdx.x];
    int e = entry >> 16, c = entry & 0xffff;
    int tid = threadIdx.x, lid = tid & 63, wv = tid >> 6;
    int nrows = 64, base = 0;
    if (e < 64) {
        int n = Wi[e]; base = Wi[64 + e];
        nrows = n - c * 64; if (nrows > 64) nrows = 64;
    }

    int kg = (lid >> 4) * 16;              // k-group byte offset (of 64B)
    int arow = wv * 16 + (lid & 15);       // token row this lane loads for A

    // A fragments: token row direct from xB
    int tA;
    if (e < 64) tA = perm[base + c * 64 + ((arow < nrows) ? arow : 0)];
    else        tA = c * 64 + arow;
    bf16x8 a[4];
    #pragma unroll
    for (int k = 0; k < 4; ++k)
        a[k] = *(const bf16x8*)(x + tA * 128 + k * 32 + (lid >> 4) * 8);

    f32x4 accd0[4], accd1[4];
    #pragma unroll
    for (int tf = 0; tf < 4; ++tf) {
        accd0[tf] = (f32x4){0.f, 0.f, 0.f, 0.f};
        accd1[tf] = (f32x4){0.f, 0.f, 0.f, 0.f};
    }

    int nsub = (e < 64) ? 1 : 2;
    for (int sub = 0; sub < nsub; ++sub) {
        int ee = (e < 64) ? e : (64 + sub);
        const ushort_t* gB = wgT + ee * 10240;
        const ushort_t* uB = wuT + ee * 10240;

        // GEMM1: per mi, B direct from global; silu fused; h -> hl
        #pragma unroll
        for (int mi = 0; mi < 5; ++mi) {
            int brow = mi * 16 + (lid & 15);
            int boff = brow * 128 + (lid >> 4) * 8;
            f32x4 ag = {0.f, 0.f, 0.f, 0.f};
            f32x4 au = {0.f, 0.f, 0.f, 0.f};
            #pragma unroll
            for (int k = 0; k < 4; ++k) {
                bf16x8 bg = *(const bf16x8*)(gB + boff + k * 32);
                bf16x8 bu = *(const bf16x8*)(uB + boff + k * 32);
                ag = __builtin_amdgcn_mfma_f32_16x16x32_bf16(a[k], bg, ag, 0, 0, 0);
                au = __builtin_amdgcn_mfma_f32_16x16x32_bf16(a[k], bu, au, 0, 0, 0);
            }
            #pragma unroll
            for (int rg = 0; rg < 4; ++rg) {
                float g = ag[rg], uu2 = au[rg];
                float h = (g / (1.f + expf(-g))) * uu2;
                int row = wv * 16 + (lid >> 4) * 4 + rg;
                int cb = (mi * 16 + (lid & 15)) * 2;
                *(ushort_t*)(hl + row * 256 + (cb ^ ((row & 7) << 4))) = f2bf(h);
            }
        }
        if (sub == 0 && tid < 128) {       // zero-pad K cols 80..95 once
            int r = tid >> 1, ch = 10 + (tid & 1);
            uint4 z = {0u, 0u, 0u, 0u};
            *(uint4*)(hl + r * 256 + ((ch * 16) ^ ((r & 7) << 4))) = z;
        }
        __syncthreads();                   // hl complete

        // GEMM2: A = wdP rows (direct global, stride 96, zero-padded), B = hl
        const ushort_t* dB = wdP + ee * 12288;
        int drow = wv * 16 + (lid & 15);
        bf16x8 ad0[3], ad1[3];
        #pragma unroll
        for (int k = 0; k < 3; ++k) {
            ad0[k] = *(const bf16x8*)(dB + drow * 96 + k * 32 + (lid >> 4) * 8);
            ad1[k] = *(const bf16x8*)(dB + (64 + drow) * 96 + k * 32 + (lid >> 4) * 8);
        }
        #pragma unroll
        for (int tf = 0; tf < 4; ++tf) {
            int brow = tf * 16 + (lid & 15);
            f32x4 c0 = accd0[tf], c1 = accd1[tf];
            #pragma unroll
            for (int k = 0; k < 3; ++k) {
                bf16x8 b = *(const bf16x8*)(hl + brow * 256 + (((k * 64) + kg) ^ ((brow & 7) << 4)));
                c0 = __builtin_amdgcn_mfma_f32_16x16x32_bf16(ad0[k], b, c0, 0, 0, 0);
                c1 = __builtin_amdgcn_mfma_f32_16x16x32_bf16(ad1[k], b, c1, 0, 0, 0);
            }
            accd0[tf] = c0; accd1[tf] = c1;
        }
        if (sub + 1 < nsub) __syncthreads();   // before rewriting hl
    }

    // epilogue: one writer per output row
    #pragma unroll
    for (int tf = 0; tf < 4; ++tf) {
        int rloc = tf * 16 + (lid & 15);
        if (rloc >= nrows) continue;
        float w = (e < 64) ? permw[base + c * 64 + rloc] : 1.0f;
        int dbase = wv * 16 + (lid >> 4) * 4;
        if (FAST) {
            ushort_t* dst = (e < 64)
                ? (yperm + (size_t)(base + c * 64 + rloc) * 128)
                : (ysh   + (size_t)(c * 64 + rloc) * 128);
            ushort_t o0[4], o1[4];
            #pragma unroll
            for (int rg = 0; rg < 4; ++rg) {
                o0[rg] = f2bf(accd0[tf][rg] * w);
                o1[rg] = f2bf(accd1[tf][rg] * w);
            }
            *(uint2*)(dst + dbase)      = *(const uint2*)o0;
            *(uint2*)(dst + 64 + dbase) = *(const uint2*)o1;
        } else {
            int t = (e < 64) ? perm[base + c * 64 + rloc] : (c * 64 + rloc);
            #pragma unroll
            for (int rg = 0; rg < 4; ++rg) {
                atomicAdd(&ybuf[t * 128 + dbase + rg],      accd0[tf][rg] * w);
                atomicAdd(&ybuf[t * 128 + 64 + dbase + rg], accd1[tf][rg] * w);
            }
        }
    }
}

// ---------------------------------------------------------------------------
// Final gather: out[t] = sum_k yperm[pos2[t*6+k]] + ysh[t].
// ---------------------------------------------------------------------------
__global__ __launch_bounds__(256) void k_final_gather(const ushort_t* yperm,
        const ushort_t* ysh, const int* pos2, void* out, const int* Wi) {
    int idx = blockIdx.x * 256 + threadIdx.x;
    int t = idx >> 4, cg = (idx & 15) * 8;
    int f32m = Wi[195];
    float acc[8];
    {
        uint4 v = *(const uint4*)(ysh + (size_t)t * 128 + cg);
        const ushort_t* u = (const ushort_t*)&v;
        #pragma unroll
        for (int j = 0; j < 8; ++j) acc[j] = bf2f(u[j]);
    }
    const int* pp = pos2 + t * 6;
    #pragma unroll
    for (int k = 0; k < 6; ++k) {
        int p = pp[k];
        uint4 v = *(const uint4*)(yperm + (size_t)p * 128 + cg);
        const ushort_t* u = (const ushort_t*)&v;
        #pragma unroll
        for (int j = 0; j < 8; ++j) acc[j] += bf2f(u[j]);
    }
    if (f32m) {
        float4 o0 = {acc[0], acc[1], acc[2], acc[3]};
        float4 o1 = {acc[4], acc[5], acc[6], acc[7]};
        float* op = (float*)out + (size_t)t * 128 + cg;
        *(float4*)op = o0; *(float4*)(op + 4) = o1;
    } else {
        ushort_t o[8];
        #pragma unroll
        for (int j = 0; j < 8; ++j) o[j] = f2bf(acc[j]);
        *(uint4*)((ushort_t*)out + (size_t)t * 128 + cg) = *(const uint4*)o;
    }
}

// fallback: read fp32 ybuf
__global__ __launch_bounds__(256) void k_final_ybuf(const float* ybuf, void* out, const int* Wi) {
    int i = blockIdx.x * 256 + threadIdx.x;
    int f32m = Wi[195];
    float4 v = ((const float4*)ybuf)[i];
    if (f32m) {
        ((float4*)out)[i] = v;
    } else {
        ushort4 o;
        o.x = f2bf(v.x); o.y = f2bf(v.y); o.z = f2bf(v.z); o.w = f2bf(v.w);
        ((ushort4*)out)[i] = o;
    }
}

// ---------------------------------------------------------------------------
extern "C" void kernel_launch(void* const* d_in, const int* in_sizes, int n_in,
                              void* d_out, int out_size, void* d_ws, size_t ws_size,
                              hipStream_t stream) {
    (void)in_sizes; (void)n_in; (void)out_size;
    const void* x   = d_in[0];
    const void* gw  = d_in[1];
    const void* wg  = d_in[2];
    const void* wu  = d_in[3];
    const void* wd  = d_in[4];
    const void* swg = d_in[5];
    const void* swu = d_in[6];
    const void* swd = d_in[7];

    char* ws = (char*)d_ws;
    int fast = (ws_size >= (size_t)NEED_FAST) ? 1 : 0;

    int*      Wi     = (int*)d_ws;
    int*      topk_i = (int*)(ws + OFF_TOPKI);
    float*    topk_w = (float*)(ws + OFF_TOPKW);
    int*      perm   = (int*)(ws + OFF_PERM);
    float*    permw  = (float*)(ws + OFF_PERMW);
    int*      pos2   = (int*)(ws + OFF_POS2);

    ushort_t* yperm = (ushort_t*)(ws + OFF_YPERM);
    ushort_t* ysh   = (ushort_t*)(ws + OFF_YSH);
    float*    ybuf  = (float*)(ws + FOFF_YBUF);
    ushort_t* wgT   = (ushort_t*)(ws + (fast ? OFF_WGT  : FOFF_WGT));
    ushort_t* wuT   = (ushort_t*)(ws + (fast ? OFF_WUT  : FOFF_WUT));
    ushort_t* wdP   = (ushort_t*)(ws + (fast ? OFF_WDP  : FOFF_WDP));
    ushort_t* xB    = (ushort_t*)(ws + (fast ? OFF_XB   : FOFF_XB));
    int*      histP = (int*)(ws + (fast ? OFF_HIST : FOFF_HIST));
    int*      boffG = (int*)(ws + (fast ? OFF_BOFF : FOFF_BOFF));

    hipMemsetAsync(d_ws, 0, 1024, stream);
    if (!fast) hipMemsetAsync(ybuf, 0, 16384 * 128 * 4, stream);

    k_detect<<<1, 64, 0, stream>>>((const ushort_t*)gw, Wi);
    k_prep<<<3 * EALL, 256, 0, stream>>>(wg, wu, wd, swg, swu, swd, wgT, wuT, wdP, Wi);
    k_gate<<<256, 1024, 0, stream>>>(x, gw, xB, topk_i, topk_w, histP, Wi);
    k_scan<<<1, 256, 0, stream>>>(Wi, histP, boffG);
    k_scatter<<<256, 256, 0, stream>>>(topk_i, topk_w, boffG, perm, permw, pos2);
    if (fast) {
        k_expert<1><<<1856, 256, 0, stream>>>(xB, wgT, wuT, wdP, Wi, perm, permw, yperm, ysh, ybuf);
        k_final_gather<<<1024, 256, 0, stream>>>(yperm, ysh, pos2, d_out, Wi);
    } else {
        k_expert<0><<<1856, 256, 0, stream>>>(xB, wgT, wuT, wdP, Wi, perm, permw, yperm, ysh, ybuf);
        k_final_ybuf<<<2048, 256, 0, stream>>>(ybuf, d_out, Wi);
    }
}

// Round 6
// 131.532 us; speedup vs baseline: 6.7885x; 1.1161x over previous
//
#include <hip/hip_runtime.h>
#include <hip/hip_bf16.h>
#include <math.h>

// ---------------------------------------------------------------------------
// DeepseekMoE: T=16384 tokens, D=128, E=64 experts top-6, M=80, shared MS=160.
// Shared expert folded in as experts 64,65; merged into ONE chunk per 128 tokens.
// R6: 128-token chunks, wave owns 32 tokens end-to-end, barrier-free k_expert;
//     16 MFMA per 8 B-loads in GEMM1; GEMM2 acc in registers across subs.
// ---------------------------------------------------------------------------

typedef unsigned short ushort_t;
typedef __attribute__((ext_vector_type(8))) short bf16x8;   // 8 bf16 = 4 VGPR
typedef __attribute__((ext_vector_type(4))) float f32x4;

#define EALL  66

// ---- fast-mode workspace byte offsets ----
#define OFF_TOPKI 16384
#define OFF_TOPKW 802816
#define OFF_PERM  1196032
#define OFF_PERMW 1589248
#define OFF_POS2  1982464
#define OFF_YPERM 2375680            // bf16 [98304][128] = 25165824
#define OFF_YSH   27541504           // bf16 [16384][128] = 4194304
#define OFF_WGT   31735808           // bf16 [66][80][128] = 1351680
#define OFF_WUT   33087488
#define OFF_WDP   34439168           // bf16 [66][128][96] = 1622016 (zero-padded)
#define OFF_XB    36061184           // bf16 [16384][128] = 4194304
#define OFF_HIST  40255488
#define OFF_BOFF  40321024
#define NEED_FAST 40386560
// ---- fallback (compact) offsets: ybuf replaces yperm/ysh ----
#define FOFF_YBUF 2375680            // float[16384*128] = 8388608
#define FOFF_WGT  10764288
#define FOFF_WUT  12115968
#define FOFF_WDP  13467648
#define FOFF_XB   15089664
#define FOFF_HIST 19283968
#define FOFF_BOFF 19349504
// int ws indices: Wi[0..63]=cnt, Wi[64..128]=excl, Wi[193]=nwork,
//   Wi[195]=f32mode, Wi[256..]=worklist (<=960 entries)

__device__ __forceinline__ float bf2f(ushort_t u) {
    unsigned int x = ((unsigned int)u) << 16;
    float f; __builtin_memcpy(&f, &x, 4); return f;
}
__device__ __forceinline__ ushort_t f2bf(float f) {
    unsigned int x; __builtin_memcpy(&x, &f, 4);
    unsigned int r = (x + 0x7fffu + ((x >> 16) & 1u)) >> 16;   // RNE
    return (ushort_t)r;
}
__device__ __forceinline__ float ldin(const void* p, int i, int f32m) {
    return f32m ? ((const float*)p)[i] : bf2f(((const ushort_t*)p)[i]);
}

// ---------------------------------------------------------------------------
__global__ __launch_bounds__(64) void k_detect(const ushort_t* gw, int* Wi) {
    int lane = threadIdx.x;
    int cnt = 0;
    #pragma unroll
    for (int j = 0; j < 4; ++j) {
        ushort_t u = gw[lane * 4 + j];
        if (((u >> 7) & 0xFF) >= 0x7C) cnt++;
    }
    #pragma unroll
    for (int off = 32; off; off >>= 1) cnt += __shfl_xor(cnt, off);
    if (lane == 0) Wi[195] = (cnt >= 8) ? 1 : 0;
}

// ---------------------------------------------------------------------------
// Prep: wgT/wuT[e][m][d] <- wg[e][d][m];  wdP[e][d][m(96,pad0)] <- wd[e][m][d]
// ---------------------------------------------------------------------------
__global__ __launch_bounds__(256) void k_prep(const void* wg, const void* wu,
        const void* wd, const void* swg, const void* swu, const void* swd,
        ushort_t* wgT, ushort_t* wuT, ushort_t* wdP, const int* Wi) {
    __shared__ float lds[128 * 81];
    int bid = blockIdx.x, tid = threadIdx.x;
    int mat = bid / EALL, e = bid % EALL;
    int f32m = Wi[195];
    if (mat < 2) {
        const void* src  = (mat == 0) ? wg  : wu;
        const void* ssrc = (mat == 0) ? swg : swu;
        for (int i = tid; i < 10240; i += 256) {
            int d = i / 80, m = i % 80;
            float v = (e < 64) ? ldin(src, e * 10240 + i, f32m)
                               : ldin(ssrc, d * 160 + (e - 64) * 80 + m, f32m);
            lds[d * 81 + m] = v;
        }
        __syncthreads();
        ushort_t* dst = ((mat == 0) ? wgT : wuT) + e * 10240;
        for (int o = tid; o < 10240; o += 256) {
            int m = o >> 7, d = o & 127;
            dst[o] = f2bf(lds[d * 81 + m]);
        }
    } else {
        for (int i = tid; i < 10240; i += 256) {
            float v = (e < 64) ? ldin(wd, e * 10240 + i, f32m)
                               : ldin(swd, (e - 64) * 10240 + i, f32m);
            int m = i >> 7, d = i & 127;
            lds[m * 129 + d] = v;
        }
        __syncthreads();
        ushort_t* dst = wdP + e * 12288;
        for (int o = tid; o < 12288; o += 256) {
            int d = o / 96, m = o % 96;
            dst[o] = (m < 80) ? f2bf(lds[m * 129 + d]) : (ushort_t)0;
        }
    }
}

// ---------------------------------------------------------------------------
// Gating: 256 blocks x 1024 threads (16 waves) x 4 tokens/wave = 64 tok/block.
// ---------------------------------------------------------------------------
__global__ __launch_bounds__(1024) void k_gate(const void* x, const void* gw,
        ushort_t* xB, int* topk_i, float* topk_w, int* histPart, const int* Wi) {
    __shared__ float gwl[64 * 130];
    __shared__ float xl[16][128];
    __shared__ int histL[64];
    int tid = threadIdx.x, b = blockIdx.x;
    int f32m = Wi[195];
    for (int i = tid; i < 8192; i += 1024)
        gwl[(i >> 7) * 130 + (i & 127)] = ldin(gw, i, f32m);
    if (tid < 64) histL[tid] = 0;
    __syncthreads();
    int wv = tid >> 6, lane = tid & 63;
    for (int q = 0; q < 4; ++q) {
        int t = b * 64 + wv * 4 + q;
        float xv0, xv1;
        if (f32m) {
            float2 v = ((const float2*)((const float*)x + t * 128))[lane];
            xv0 = v.x; xv1 = v.y;
        } else {
            unsigned int pr = *(const unsigned int*)((const ushort_t*)x + t * 128 + lane * 2);
            xv0 = bf2f((ushort_t)(pr & 0xffffu));
            xv1 = bf2f((ushort_t)(pr >> 16));
        }
        float2 xw; xw.x = xv0; xw.y = xv1;
        *(float2*)&xl[wv][lane * 2] = xw;
        unsigned int packed = (unsigned int)f2bf(xv0) | ((unsigned int)f2bf(xv1) << 16);
        *(unsigned int*)(xB + t * 128 + lane * 2) = packed;
        float acc = 0.f;
        #pragma unroll
        for (int d2 = 0; d2 < 64; ++d2) {
            float2 xv = *(const float2*)&xl[wv][d2 * 2];
            float2 gv = *(const float2*)&gwl[lane * 130 + d2 * 2];
            acc = fmaf(xv.x, gv.x, acc);
            acc = fmaf(xv.y, gv.y, acc);
        }
        float mx = acc;
        #pragma unroll
        for (int off = 32; off; off >>= 1) mx = fmaxf(mx, __shfl_xor(mx, off));
        float p = expf(acc - mx);
        float sm = p;
        #pragma unroll
        for (int off = 32; off; off >>= 1) sm += __shfl_xor(sm, off);
        float sc = p / sm;
        float cur = sc;
        float wk[6]; int ik[6];
        #pragma unroll
        for (int k = 0; k < 6; ++k) {
            float bv = cur; int bi = lane;
            #pragma unroll
            for (int off = 1; off < 64; off <<= 1) {
                float ov = __shfl_xor(bv, off); int oi = __shfl_xor(bi, off);
                if (ov > bv || (ov == bv && oi < bi)) { bv = ov; bi = oi; }
            }
            wk[k] = bv; ik[k] = bi;
            if (lane == bi) cur = -INFINITY;
        }
        if (lane == 0) {
            float den = wk[0] + wk[1] + wk[2] + wk[3] + wk[4] + wk[5] + 1e-20f;
            #pragma unroll
            for (int k = 0; k < 6; ++k) {
                topk_i[t * 6 + k] = ik[k];
                topk_w[t * 6 + k] = wk[k] / den;
                atomicAdd(&histL[ik[k]], 1);
            }
        }
    }
    __syncthreads();
    if (tid < 64) histPart[tid * 256 + b] = histL[tid];
}

// ---------------------------------------------------------------------------
// Scan (1 block): per-expert scan, bases, worklist (128-token chunks).
// ---------------------------------------------------------------------------
__global__ __launch_bounds__(256) void k_scan(int* Wi, const int* histPart, int* boffG) {
    __shared__ int hl[16384];
    __shared__ int cntL[64], exclL[64], chxL[65];
    int tid = threadIdx.x, lane = tid & 63, wv = tid >> 6;
    for (int j = tid; j < 16384; j += 256) hl[j] = histPart[j];
    __syncthreads();
    for (int ei = 0; ei < 16; ++ei) {
        int e = wv * 16 + ei;
        int carry = 0;
        for (int r = 0; r < 4; ++r) {
            int v = hl[e * 256 + r * 64 + lane];
            int incl = v;
            #pragma unroll
            for (int off = 1; off < 64; off <<= 1) {
                int ts = __shfl_up(incl, off);
                if (lane >= off) incl += ts;
            }
            hl[e * 256 + r * 64 + lane] = carry + incl - v;
            carry += __shfl(incl, 63);
        }
        if (lane == 0) cntL[e] = carry;
    }
    __syncthreads();
    if (tid == 0) {
        int s = 0, cs = 0;
        for (int e = 0; e < 64; ++e) {
            exclL[e] = s; s += cntL[e];
            chxL[e] = cs; cs += (cntL[e] + 127) >> 7;
        }
        chxL[64] = cs;
        Wi[128] = s;
        Wi[193] = cs + 128;   // nwork (128 merged shared chunks)
    }
    __syncthreads();
    if (tid < 64) { Wi[tid] = cntL[tid]; Wi[64 + tid] = exclL[tid]; }
    for (int j = tid; j < 16384; j += 256) boffG[j] = hl[j] + exclL[j >> 8];
    if (tid < 64) {
        int e = tid, nc = (cntL[e] + 127) >> 7, bb = chxL[e];
        for (int c = 0; c < nc; ++c) Wi[256 + bb + c] = (e << 16) | c;
    }
    int R = chxL[64];
    for (int j = tid; j < 128; j += 256)
        Wi[256 + R + j] = (64 << 16) | j;
}

// ---------------------------------------------------------------------------
// Scatter: LDS counters seeded from boffG; records pos2 for the gather.
// ---------------------------------------------------------------------------
__global__ __launch_bounds__(256) void k_scatter(const int* topk_i, const float* topk_w,
        const int* boffG, int* perm, float* permw, int* pos2) {
    __shared__ int lcur[64];
    int tid = threadIdx.x, b = blockIdx.x;
    if (tid < 64) lcur[tid] = boffG[tid * 256 + b];
    __syncthreads();
    for (int i = tid; i < 384; i += 256) {
        int g = b * 384 + i;
        int e = topk_i[g];
        float w = topk_w[g];
        int p = atomicAdd(&lcur[e], 1);
        perm[p]  = b * 64 + i / 6;
        permw[p] = w;
        pos2[g]  = p;
    }
}

// ---------------------------------------------------------------------------
// Expert MLP v3: 128-token chunks, 4 waves, wave owns 32 tokens end-to-end.
// NO __syncthreads: each wave writes/reads only its own 32 hl rows (in-order
// per-wave DS pipe). A frags persistent; GEMM2 acc[8][2] persists across the
// shared expert's two halves. B direct from L2-resident pre-transposed weights.
// hl swizzle: byte = row*256 + (colByte ^ ((row&7)<<4)).
// ---------------------------------------------------------------------------
template<int FAST>
__global__ __launch_bounds__(256) void k_expert(const ushort_t* x, const ushort_t* wgT,
        const ushort_t* wuT, const ushort_t* wdP, const int* Wi, const int* perm,
        const float* permw, ushort_t* yperm, ushort_t* ysh, float* ybuf) {
    __shared__ __align__(16) char hl[32768];   // 128 rows x 256B (K padded to 96)

    if (blockIdx.x >= Wi[193]) return;
    int entry = Wi[256 + blockIdx.x];
    int e = entry >> 16, c = entry & 0xffff;
    int tid = threadIdx.x, lid = tid & 63, wv = tid >> 6;
    int nrows = 128, base = 0;
    if (e < 64) {
        int n = Wi[e]; base = Wi[64 + e];
        nrows = n - c * 128; if (nrows > 128) nrows = 128;
    }

    int kg  = (lid >> 4) * 16;    // k byte offset within 64B k-group
    int kq8 = (lid >> 4) * 8;     // k element offset for 8-elem slices

    // A fragments: 2 tile-rows x 4 k (persistent)
    bf16x8 a[2][4];
    #pragma unroll
    for (int tr = 0; tr < 2; ++tr) {
        int arow = wv * 32 + tr * 16 + (lid & 15);
        int r = (arow < nrows) ? arow : (nrows - 1);
        int t = (e < 64) ? perm[base + c * 128 + r] : (c * 128 + arow);
        #pragma unroll
        for (int k = 0; k < 4; ++k)
            a[tr][k] = *(const bf16x8*)(x + t * 128 + k * 32 + kq8);
    }

    f32x4 acc[8][2];
    #pragma unroll
    for (int dt = 0; dt < 8; ++dt) {
        acc[dt][0] = (f32x4){0.f, 0.f, 0.f, 0.f};
        acc[dt][1] = (f32x4){0.f, 0.f, 0.f, 0.f};
    }

    int nsub = (e < 64) ? 1 : 2;
    for (int sub = 0; sub < nsub; ++sub) {
        int ee = (e < 64) ? e : (64 + sub);
        const ushort_t* gB = wgT + ee * 10240;
        const ushort_t* uB = wuT + ee * 10240;

        // GEMM1: per mi, 8 B-loads feed 16 MFMAs; silu fused; h -> own hl rows
        #pragma unroll
        for (int mi = 0; mi < 5; ++mi) {
            int boff = (mi * 16 + (lid & 15)) * 128 + kq8;
            bf16x8 bg[4], bu[4];
            #pragma unroll
            for (int k = 0; k < 4; ++k) {
                bg[k] = *(const bf16x8*)(gB + boff + k * 32);
                bu[k] = *(const bf16x8*)(uB + boff + k * 32);
            }
            f32x4 ag[2], au[2];
            #pragma unroll
            for (int tr = 0; tr < 2; ++tr) {
                ag[tr] = (f32x4){0.f, 0.f, 0.f, 0.f};
                au[tr] = (f32x4){0.f, 0.f, 0.f, 0.f};
            }
            #pragma unroll
            for (int k = 0; k < 4; ++k) {
                #pragma unroll
                for (int tr = 0; tr < 2; ++tr) {
                    ag[tr] = __builtin_amdgcn_mfma_f32_16x16x32_bf16(a[tr][k], bg[k], ag[tr], 0, 0, 0);
                    au[tr] = __builtin_amdgcn_mfma_f32_16x16x32_bf16(a[tr][k], bu[k], au[tr], 0, 0, 0);
                }
            }
            #pragma unroll
            for (int tr = 0; tr < 2; ++tr) {
                #pragma unroll
                for (int rg = 0; rg < 4; ++rg) {
                    float g = ag[tr][rg], uu2 = au[tr][rg];
                    float h = (g / (1.f + expf(-g))) * uu2;
                    int row = wv * 32 + tr * 16 + (lid >> 4) * 4 + rg;
                    int cb = (mi * 16 + (lid & 15)) * 2;
                    *(ushort_t*)(hl + row * 256 + (cb ^ ((row & 7) << 4))) = f2bf(h);
                }
            }
        }
        if (sub == 0) {   // zero-pad own rows, K cols 80..95 (one uint4 per lane)
            int r = wv * 32 + (lid >> 1), ch = 10 + (lid & 1);
            uint4 z = {0u, 0u, 0u, 0u};
            *(uint4*)(hl + r * 256 + ((ch * 16) ^ ((r & 7) << 4))) = z;
        }

        // GEMM2: A = wdP rows (direct global, stride 96), B = own hl rows
        const ushort_t* dB = wdP + ee * 12288;
        #pragma unroll
        for (int dt = 0; dt < 8; ++dt) {
            int drow = dt * 16 + (lid & 15);
            bf16x8 ad[3];
            #pragma unroll
            for (int k = 0; k < 3; ++k)
                ad[k] = *(const bf16x8*)(dB + drow * 96 + k * 32 + kq8);
            #pragma unroll
            for (int tf = 0; tf < 2; ++tf) {
                int brow = wv * 32 + tf * 16 + (lid & 15);
                f32x4 cc = acc[dt][tf];
                #pragma unroll
                for (int k = 0; k < 3; ++k) {
                    bf16x8 b = *(const bf16x8*)(hl + brow * 256 + (((k * 64) + kg) ^ ((brow & 7) << 4)));
                    cc = __builtin_amdgcn_mfma_f32_16x16x32_bf16(ad[k], b, cc, 0, 0, 0);
                }
                acc[dt][tf] = cc;
            }
        }
    }

    // epilogue: one writer per output row
    #pragma unroll
    for (int tf = 0; tf < 2; ++tf) {
        int rloc = wv * 32 + tf * 16 + (lid & 15);
        if (rloc >= nrows) continue;
        float w = (e < 64) ? permw[base + c * 128 + rloc] : 1.0f;
        if (FAST) {
            ushort_t* dst = (e < 64)
                ? (yperm + (size_t)(base + c * 128 + rloc) * 128)
                : (ysh   + (size_t)(c * 128 + rloc) * 128);
            #pragma unroll
            for (int dt = 0; dt < 8; ++dt) {
                int d0 = dt * 16 + (lid >> 4) * 4;
                ushort_t o[4];
                #pragma unroll
                for (int rg = 0; rg < 4; ++rg) o[rg] = f2bf(acc[dt][tf][rg] * w);
                *(uint2*)(dst + d0) = *(const uint2*)o;
            }
        } else {
            int t = (e < 64) ? perm[base + c * 128 + rloc] : (c * 128 + rloc);
            #pragma unroll
            for (int dt = 0; dt < 8; ++dt) {
                int d0 = dt * 16 + (lid >> 4) * 4;
                #pragma unroll
                for (int rg = 0; rg < 4; ++rg)
                    atomicAdd(&ybuf[t * 128 + d0 + rg], acc[dt][tf][rg] * w);
            }
        }
    }
}

// ---------------------------------------------------------------------------
// Final gather: out[t] = sum_k yperm[pos2[t*6+k]] + ysh[t].
// ---------------------------------------------------------------------------
__global__ __launch_bounds__(256) void k_final_gather(const ushort_t* yperm,
        const ushort_t* ysh, const int* pos2, void* out, const int* Wi) {
    int idx = blockIdx.x * 256 + threadIdx.x;
    int t = idx >> 4, cg = (idx & 15) * 8;
    int f32m = Wi[195];
    float acc[8];
    {
        uint4 v = *(const uint4*)(ysh + (size_t)t * 128 + cg);
        const ushort_t* u = (const ushort_t*)&v;
        #pragma unroll
        for (int j = 0; j < 8; ++j) acc[j] = bf2f(u[j]);
    }
    const int* pp = pos2 + t * 6;
    #pragma unroll
    for (int k = 0; k < 6; ++k) {
        int p = pp[k];
        uint4 v = *(const uint4*)(yperm + (size_t)p * 128 + cg);
        const ushort_t* u = (const ushort_t*)&v;
        #pragma unroll
        for (int j = 0; j < 8; ++j) acc[j] += bf2f(u[j]);
    }
    if (f32m) {
        float4 o0 = {acc[0], acc[1], acc[2], acc[3]};
        float4 o1 = {acc[4], acc[5], acc[6], acc[7]};
        float* op = (float*)out + (size_t)t * 128 + cg;
        *(float4*)op = o0; *(float4*)(op + 4) = o1;
    } else {
        ushort_t o[8];
        #pragma unroll
        for (int j = 0; j < 8; ++j) o[j] = f2bf(acc[j]);
        *(uint4*)((ushort_t*)out + (size_t)t * 128 + cg) = *(const uint4*)o;
    }
}

// fallback: read fp32 ybuf
__global__ __launch_bounds__(256) void k_final_ybuf(const float* ybuf, void* out, const int* Wi) {
    int i = blockIdx.x * 256 + threadIdx.x;
    int f32m = Wi[195];
    float4 v = ((const float4*)ybuf)[i];
    if (f32m) {
        ((float4*)out)[i] = v;
    } else {
        ushort4 o;
        o.x = f2bf(v.x); o.y = f2bf(v.y); o.z = f2bf(v.z); o.w = f2bf(v.w);
        ((ushort4*)out)[i] = o;
    }
}

// ---------------------------------------------------------------------------
extern "C" void kernel_launch(void* const* d_in, const int* in_sizes, int n_in,
                              void* d_out, int out_size, void* d_ws, size_t ws_size,
                              hipStream_t stream) {
    (void)in_sizes; (void)n_in; (void)out_size;
    const void* x   = d_in[0];
    const void* gw  = d_in[1];
    const void* wg  = d_in[2];
    const void* wu  = d_in[3];
    const void* wd  = d_in[4];
    const void* swg = d_in[5];
    const void* swu = d_in[6];
    const void* swd = d_in[7];

    char* ws = (char*)d_ws;
    int fast = (ws_size >= (size_t)NEED_FAST) ? 1 : 0;

    int*      Wi     = (int*)d_ws;
    int*      topk_i = (int*)(ws + OFF_TOPKI);
    float*    topk_w = (float*)(ws + OFF_TOPKW);
    int*      perm   = (int*)(ws + OFF_PERM);
    float*    permw  = (float*)(ws + OFF_PERMW);
    int*      pos2   = (int*)(ws + OFF_POS2);

    ushort_t* yperm = (ushort_t*)(ws + OFF_YPERM);
    ushort_t* ysh   = (ushort_t*)(ws + OFF_YSH);
    float*    ybuf  = (float*)(ws + FOFF_YBUF);
    ushort_t* wgT   = (ushort_t*)(ws + (fast ? OFF_WGT  : FOFF_WGT));
    ushort_t* wuT   = (ushort_t*)(ws + (fast ? OFF_WUT  : FOFF_WUT));
    ushort_t* wdP   = (ushort_t*)(ws + (fast ? OFF_WDP  : FOFF_WDP));
    ushort_t* xB    = (ushort_t*)(ws + (fast ? OFF_XB   : FOFF_XB));
    int*      histP = (int*)(ws + (fast ? OFF_HIST : FOFF_HIST));
    int*      boffG = (int*)(ws + (fast ? OFF_BOFF : FOFF_BOFF));

    hipMemsetAsync(d_ws, 0, 1024, stream);
    if (!fast) hipMemsetAsync(ybuf, 0, 16384 * 128 * 4, stream);

    k_detect<<<1, 64, 0, stream>>>((const ushort_t*)gw, Wi);
    k_prep<<<3 * EALL, 256, 0, stream>>>(wg, wu, wd, swg, swu, swd, wgT, wuT, wdP, Wi);
    k_gate<<<256, 1024, 0, stream>>>(x, gw, xB, topk_i, topk_w, histP, Wi);
    k_scan<<<1, 256, 0, stream>>>(Wi, histP, boffG);
    k_scatter<<<256, 256, 0, stream>>>(topk_i, topk_w, boffG, perm, permw, pos2);
    if (fast) {
        k_expert<1><<<960, 256, 0, stream>>>(xB, wgT, wuT, wdP, Wi, perm, permw, yperm, ysh, ybuf);
        k_final_gather<<<1024, 256, 0, stream>>>(yperm, ysh, pos2, d_out, Wi);
    } else {
        k_expert<0><<<960, 256, 0, stream>>>(xB, wgT, wuT, wdP, Wi, perm, permw, yperm, ysh, ybuf);
        k_final_ybuf<<<2048, 256, 0, stream>>>(ybuf, d_out, Wi);
    }
}

// Round 7
// 117.133 us; speedup vs baseline: 7.6229x; 1.1229x over previous
//
#include <hip/hip_runtime.h>
#include <hip/hip_bf16.h>
#include <math.h>

// ---------------------------------------------------------------------------
// DeepseekMoE: T=16384 tokens, D=128, E=64 experts top-6, M=80, shared MS=160.
// R7: uniform block durations — shared expert = 256 chunks of 64 tokens x 2
//     halves (same FLOPs as a routed 128-token chunk). k_prep 4x blocks.
//     k_detect folded inline into consumers (one fewer dispatch, no memset).
// ---------------------------------------------------------------------------

typedef unsigned short ushort_t;
typedef __attribute__((ext_vector_type(8))) short bf16x8;   // 8 bf16 = 4 VGPR
typedef __attribute__((ext_vector_type(4))) float f32x4;

#define EALL  66

// ---- fast-mode workspace byte offsets ----
#define OFF_TOPKI 16384
#define OFF_TOPKW 802816
#define OFF_PERM  1196032
#define OFF_PERMW 1589248
#define OFF_POS2  1982464
#define OFF_YPERM 2375680            // bf16 [98304][128] = 25165824
#define OFF_YSH   27541504           // bf16 [16384][128] = 4194304
#define OFF_WGT   31735808           // bf16 [66][80][128] = 1351680
#define OFF_WUT   33087488
#define OFF_WDP   34439168           // bf16 [66][128][96] = 1622016 (zero-padded)
#define OFF_XB    36061184           // bf16 [16384][128] = 4194304
#define OFF_HIST  40255488
#define OFF_BOFF  40321024
#define NEED_FAST 40386560
// ---- fallback (compact) offsets: ybuf replaces yperm/ysh ----
#define FOFF_YBUF 2375680            // float[16384*128] = 8388608
#define FOFF_WGT  10764288
#define FOFF_WUT  12115968
#define FOFF_WDP  13467648
#define FOFF_XB   15089664
#define FOFF_HIST 19283968
#define FOFF_BOFF 19349504
// int ws indices: Wi[0..63]=cnt, Wi[64..128]=excl, Wi[193]=nwork,
//   Wi[256..]=worklist (<=1087 entries)

__device__ __forceinline__ float bf2f(ushort_t u) {
    unsigned int x = ((unsigned int)u) << 16;
    float f; __builtin_memcpy(&f, &x, 4); return f;
}
__device__ __forceinline__ ushort_t f2bf(float f) {
    unsigned int x; __builtin_memcpy(&x, &f, 4);
    unsigned int r = (x + 0x7fffu + ((x >> 16) & 1u)) >> 16;   // RNE
    return (ushort_t)r;
}
__device__ __forceinline__ float ldin(const void* p, int i, int f32m) {
    return f32m ? ((const float*)p)[i] : bf2f(((const ushort_t*)p)[i]);
}
// dtype detect from gate_w: |gw| < 2^-3 so bf16 halves never have exponent
// field >= 0x7C; f32 mantissa low-halves are ~uniform (~52% do). Per-wave.
__device__ __forceinline__ int detect_f32m(const ushort_t* gw) {
    int lane = threadIdx.x & 63;
    int cnt = 0;
    #pragma unroll
    for (int j = 0; j < 4; ++j) {
        ushort_t u = gw[lane * 4 + j];
        if (((u >> 7) & 0xFF) >= 0x7C) cnt++;
    }
    #pragma unroll
    for (int off = 32; off; off >>= 1) cnt += __shfl_xor(cnt, off);
    return (cnt >= 8) ? 1 : 0;
}

// ---------------------------------------------------------------------------
// Prep (4 quarter-slabs per matrix): wgT/wuT[e][m][d] <- wg[e][d][m];
// wdP[e][d][m(96,pad0)] <- wd[e][m][d].
// ---------------------------------------------------------------------------
__global__ __launch_bounds__(256) void k_prep(const void* wg, const void* wu,
        const void* wd, const void* swg, const void* swu, const void* swd,
        const ushort_t* gwDet,
        ushort_t* wgT, ushort_t* wuT, ushort_t* wdP) {
    __shared__ float lds[32 * 81];    // also viewed as [20][129]
    int bid = blockIdx.x, tid = threadIdx.x;
    int mat = bid / (EALL * 4);
    int rem = bid % (EALL * 4);
    int e = rem >> 2, q = rem & 3;
    int f32m = detect_f32m(gwDet);
    if (mat < 2) {
        const void* src  = (mat == 0) ? wg  : wu;
        const void* ssrc = (mat == 0) ? swg : swu;
        // slab: d in [q*32, q*32+32), m in [0,80)
        for (int i = tid; i < 2560; i += 256) {
            int d = i / 80, m = i % 80;
            float v = (e < 64) ? ldin(src, e * 10240 + (q * 32 + d) * 80 + m, f32m)
                               : ldin(ssrc, (q * 32 + d) * 160 + (e - 64) * 80 + m, f32m);
            lds[d * 81 + m] = v;
        }
        __syncthreads();
        ushort_t* dst = ((mat == 0) ? wgT : wuT) + e * 10240;
        for (int o = tid; o < 2560; o += 256) {
            int m = o >> 5, d = o & 31;
            dst[m * 128 + q * 32 + d] = f2bf(lds[d * 81 + m]);
        }
    } else {
        // slab: m in [q*20, q*20+20), d in [0,128)
        for (int i = tid; i < 2560; i += 256) {
            int m = i >> 7, d = i & 127;
            float v = (e < 64) ? ldin(wd, e * 10240 + (q * 20 + m) * 128 + d, f32m)
                               : ldin(swd, (e - 64) * 10240 + (q * 20 + m) * 128 + d, f32m);
            lds[m * 129 + d] = v;
        }
        __syncthreads();
        ushort_t* dst = wdP + e * 12288;
        for (int o = tid; o < 2560; o += 256) {
            int d = o / 20, m = o % 20;
            dst[d * 96 + q * 20 + m] = f2bf(lds[m * 129 + d]);
        }
        if (q == 3) {   // zero-pad cols 80..95
            for (int o2 = tid; o2 < 2048; o2 += 256) {
                int d = o2 >> 4, m = 80 + (o2 & 15);
                dst[d * 96 + m] = (ushort_t)0;
            }
        }
    }
}

// ---------------------------------------------------------------------------
// Gating: 256 blocks x 1024 threads (16 waves) x 4 tokens/wave = 64 tok/block.
// f32 dot (matches reference top-k), softmax + top-6 + renorm.
// Per-block LDS histogram -> histPart. Emits xB (bf16 x) as side product.
// ---------------------------------------------------------------------------
__global__ __launch_bounds__(1024) void k_gate(const void* x, const void* gw,
        ushort_t* xB, int* topk_i, float* topk_w, int* histPart) {
    __shared__ float gwl[64 * 130];
    __shared__ float xl[16][128];
    __shared__ int histL[64];
    int tid = threadIdx.x, b = blockIdx.x;
    int f32m = detect_f32m((const ushort_t*)gw);
    for (int i = tid; i < 8192; i += 1024)
        gwl[(i >> 7) * 130 + (i & 127)] = ldin(gw, i, f32m);
    if (tid < 64) histL[tid] = 0;
    __syncthreads();
    int wv = tid >> 6, lane = tid & 63;
    for (int q = 0; q < 4; ++q) {
        int t = b * 64 + wv * 4 + q;
        float xv0, xv1;
        if (f32m) {
            float2 v = ((const float2*)((const float*)x + t * 128))[lane];
            xv0 = v.x; xv1 = v.y;
        } else {
            unsigned int pr = *(const unsigned int*)((const ushort_t*)x + t * 128 + lane * 2);
            xv0 = bf2f((ushort_t)(pr & 0xffffu));
            xv1 = bf2f((ushort_t)(pr >> 16));
        }
        float2 xw; xw.x = xv0; xw.y = xv1;
        *(float2*)&xl[wv][lane * 2] = xw;
        unsigned int packed = (unsigned int)f2bf(xv0) | ((unsigned int)f2bf(xv1) << 16);
        *(unsigned int*)(xB + t * 128 + lane * 2) = packed;
        float acc = 0.f;
        #pragma unroll
        for (int d2 = 0; d2 < 64; ++d2) {
            float2 xv = *(const float2*)&xl[wv][d2 * 2];
            float2 gv = *(const float2*)&gwl[lane * 130 + d2 * 2];
            acc = fmaf(xv.x, gv.x, acc);
            acc = fmaf(xv.y, gv.y, acc);
        }
        float mx = acc;
        #pragma unroll
        for (int off = 32; off; off >>= 1) mx = fmaxf(mx, __shfl_xor(mx, off));
        float p = expf(acc - mx);
        float sm = p;
        #pragma unroll
        for (int off = 32; off; off >>= 1) sm += __shfl_xor(sm, off);
        float sc = p / sm;
        float cur = sc;
        float wk[6]; int ik[6];
        #pragma unroll
        for (int k = 0; k < 6; ++k) {
            float bv = cur; int bi = lane;
            #pragma unroll
            for (int off = 1; off < 64; off <<= 1) {
                float ov = __shfl_xor(bv, off); int oi = __shfl_xor(bi, off);
                if (ov > bv || (ov == bv && oi < bi)) { bv = ov; bi = oi; }
            }
            wk[k] = bv; ik[k] = bi;
            if (lane == bi) cur = -INFINITY;
        }
        if (lane == 0) {
            float den = wk[0] + wk[1] + wk[2] + wk[3] + wk[4] + wk[5] + 1e-20f;
            #pragma unroll
            for (int k = 0; k < 6; ++k) {
                topk_i[t * 6 + k] = ik[k];
                topk_w[t * 6 + k] = wk[k] / den;
                atomicAdd(&histL[ik[k]], 1);
            }
        }
    }
    __syncthreads();
    if (tid < 64) histPart[tid * 256 + b] = histL[tid];
}

// ---------------------------------------------------------------------------
// Scan (1 block): per-expert scan over gate blocks, bases, worklist.
// Routed: 128-token chunks. Shared: 256 chunks of 64 tokens (e encoded 64).
// ---------------------------------------------------------------------------
__global__ __launch_bounds__(256) void k_scan(int* Wi, const int* histPart, int* boffG) {
    __shared__ int hl[16384];
    __shared__ int cntL[64], exclL[64], chxL[65];
    int tid = threadIdx.x, lane = tid & 63, wv = tid >> 6;
    for (int j = tid; j < 16384; j += 256) hl[j] = histPart[j];
    __syncthreads();
    for (int ei = 0; ei < 16; ++ei) {
        int e = wv * 16 + ei;
        int carry = 0;
        for (int r = 0; r < 4; ++r) {
            int v = hl[e * 256 + r * 64 + lane];
            int incl = v;
            #pragma unroll
            for (int off = 1; off < 64; off <<= 1) {
                int ts = __shfl_up(incl, off);
                if (lane >= off) incl += ts;
            }
            hl[e * 256 + r * 64 + lane] = carry + incl - v;
            carry += __shfl(incl, 63);
        }
        if (lane == 0) cntL[e] = carry;
    }
    __syncthreads();
    if (tid == 0) {
        int s = 0, cs = 0;
        for (int e = 0; e < 64; ++e) {
            exclL[e] = s; s += cntL[e];
            chxL[e] = cs; cs += (cntL[e] + 127) >> 7;
        }
        chxL[64] = cs;
        Wi[128] = s;
        Wi[193] = cs + 256;   // nwork (+256 shared 64-token chunks)
    }
    __syncthreads();
    if (tid < 64) { Wi[tid] = cntL[tid]; Wi[64 + tid] = exclL[tid]; }
    for (int j = tid; j < 16384; j += 256) boffG[j] = hl[j] + exclL[j >> 8];
    if (tid < 64) {
        int e = tid, nc = (cntL[e] + 127) >> 7, bb = chxL[e];
        for (int c = 0; c < nc; ++c) Wi[256 + bb + c] = (e << 16) | c;
    }
    int R = chxL[64];
    for (int j = tid; j < 256; j += 256)
        Wi[256 + R + j] = (64 << 16) | j;
}

// ---------------------------------------------------------------------------
// Scatter: LDS counters seeded from boffG; records pos2 for the gather.
// ---------------------------------------------------------------------------
__global__ __launch_bounds__(256) void k_scatter(const int* topk_i, const float* topk_w,
        const int* boffG, int* perm, float* permw, int* pos2) {
    __shared__ int lcur[64];
    int tid = threadIdx.x, b = blockIdx.x;
    if (tid < 64) lcur[tid] = boffG[tid * 256 + b];
    __syncthreads();
    for (int i = tid; i < 384; i += 256) {
        int g = b * 384 + i;
        int e = topk_i[g];
        float w = topk_w[g];
        int p = atomicAdd(&lcur[e], 1);
        perm[p]  = b * 64 + i / 6;
        permw[p] = w;
        pos2[g]  = p;
    }
}

// ---------------------------------------------------------------------------
// Expert MLP v4: uniform blocks. Routed: 128-token chunk, wave owns 32 tokens
// (TR=2, nsub=1). Shared (e==64): 64-token chunk, wave owns 16 tokens, both
// halves accumulated (TR=1, nsub=2) == same FLOPs as routed. Barrier-free:
// each wave touches only its own hl rows. B direct from L2-resident weights.
// hl swizzle: byte = row*256 + (colByte ^ ((row&7)<<4)).
// ---------------------------------------------------------------------------
template<int FAST>
__global__ __launch_bounds__(256, 4) void k_expert(const ushort_t* x, const ushort_t* wgT,
        const ushort_t* wuT, const ushort_t* wdP, const int* Wi, const int* perm,
        const float* permw, ushort_t* yperm, ushort_t* ysh, float* ybuf) {
    __shared__ __align__(16) char hl[32768];   // 128 rows x 256B (K padded to 96)

    if (blockIdx.x >= Wi[193]) return;
    int entry = Wi[256 + blockIdx.x];
    int e = entry >> 16, c = entry & 0xffff;
    int tid = threadIdx.x, lid = tid & 63, wv = tid >> 6;
    int kg  = (lid >> 4) * 16;    // k byte offset within 64B k-group
    int kq8 = (lid >> 4) * 8;     // k element offset for 8-elem slices

    if (e < 64) {
        // ---------------- routed: 128-token chunk ----------------
        int n = Wi[e], base = Wi[64 + e];
        int nrows = n - c * 128; if (nrows > 128) nrows = 128;

        bf16x8 a[2][4];
        #pragma unroll
        for (int tr = 0; tr < 2; ++tr) {
            int arow = wv * 32 + tr * 16 + (lid & 15);
            int r = (arow < nrows) ? arow : (nrows - 1);
            int t = perm[base + c * 128 + r];
            #pragma unroll
            for (int k = 0; k < 4; ++k)
                a[tr][k] = *(const bf16x8*)(x + t * 128 + k * 32 + kq8);
        }

        const ushort_t* gB = wgT + e * 10240;
        const ushort_t* uB = wuT + e * 10240;
        #pragma unroll
        for (int mi = 0; mi < 5; ++mi) {
            int boff = (mi * 16 + (lid & 15)) * 128 + kq8;
            bf16x8 bg[4], bu[4];
            #pragma unroll
            for (int k = 0; k < 4; ++k) {
                bg[k] = *(const bf16x8*)(gB + boff + k * 32);
                bu[k] = *(const bf16x8*)(uB + boff + k * 32);
            }
            f32x4 ag[2], au[2];
            #pragma unroll
            for (int tr = 0; tr < 2; ++tr) {
                ag[tr] = (f32x4){0.f, 0.f, 0.f, 0.f};
                au[tr] = (f32x4){0.f, 0.f, 0.f, 0.f};
            }
            #pragma unroll
            for (int k = 0; k < 4; ++k) {
                #pragma unroll
                for (int tr = 0; tr < 2; ++tr) {
                    ag[tr] = __builtin_amdgcn_mfma_f32_16x16x32_bf16(a[tr][k], bg[k], ag[tr], 0, 0, 0);
                    au[tr] = __builtin_amdgcn_mfma_f32_16x16x32_bf16(a[tr][k], bu[k], au[tr], 0, 0, 0);
                }
            }
            #pragma unroll
            for (int tr = 0; tr < 2; ++tr) {
                #pragma unroll
                for (int rg = 0; rg < 4; ++rg) {
                    float g = ag[tr][rg], uu2 = au[tr][rg];
                    float h = (g / (1.f + expf(-g))) * uu2;
                    int row = wv * 32 + tr * 16 + (lid >> 4) * 4 + rg;
                    int cb = (mi * 16 + (lid & 15)) * 2;
                    *(ushort_t*)(hl + row * 256 + (cb ^ ((row & 7) << 4))) = f2bf(h);
                }
            }
        }
        {   // zero-pad own rows, K cols 80..95
            int r = wv * 32 + (lid >> 1), ch = 10 + (lid & 1);
            uint4 z = {0u, 0u, 0u, 0u};
            *(uint4*)(hl + r * 256 + ((ch * 16) ^ ((r & 7) << 4))) = z;
        }

        f32x4 acc[8][2];
        #pragma unroll
        for (int dt = 0; dt < 8; ++dt) {
            acc[dt][0] = (f32x4){0.f, 0.f, 0.f, 0.f};
            acc[dt][1] = (f32x4){0.f, 0.f, 0.f, 0.f};
        }
        const ushort_t* dB = wdP + e * 12288;
        #pragma unroll
        for (int dt = 0; dt < 8; ++dt) {
            int drow = dt * 16 + (lid & 15);
            bf16x8 ad[3];
            #pragma unroll
            for (int k = 0; k < 3; ++k)
                ad[k] = *(const bf16x8*)(dB + drow * 96 + k * 32 + kq8);
            #pragma unroll
            for (int tf = 0; tf < 2; ++tf) {
                int brow = wv * 32 + tf * 16 + (lid & 15);
                f32x4 cc = acc[dt][tf];
                #pragma unroll
                for (int k = 0; k < 3; ++k) {
                    bf16x8 b = *(const bf16x8*)(hl + brow * 256 + (((k * 64) + kg) ^ ((brow & 7) << 4)));
                    cc = __builtin_amdgcn_mfma_f32_16x16x32_bf16(ad[k], b, cc, 0, 0, 0);
                }
                acc[dt][tf] = cc;
            }
        }

        #pragma unroll
        for (int tf = 0; tf < 2; ++tf) {
            int rloc = wv * 32 + tf * 16 + (lid & 15);
            if (rloc >= nrows) continue;
            float w = permw[base + c * 128 + rloc];
            if (FAST) {
                ushort_t* dst = yperm + (size_t)(base + c * 128 + rloc) * 128;
                #pragma unroll
                for (int dt = 0; dt < 8; ++dt) {
                    int d0 = dt * 16 + (lid >> 4) * 4;
                    ushort_t o[4];
                    #pragma unroll
                    for (int rg = 0; rg < 4; ++rg) o[rg] = f2bf(acc[dt][tf][rg] * w);
                    *(uint2*)(dst + d0) = *(const uint2*)o;
                }
            } else {
                int t = perm[base + c * 128 + rloc];
                #pragma unroll
                for (int dt = 0; dt < 8; ++dt) {
                    int d0 = dt * 16 + (lid >> 4) * 4;
                    #pragma unroll
                    for (int rg = 0; rg < 4; ++rg)
                        atomicAdd(&ybuf[t * 128 + d0 + rg], acc[dt][tf][rg] * w);
                }
            }
        }
    } else {
        // ---------------- shared: 64-token chunk, 2 halves ----------------
        bf16x8 a1[4];
        int arow = wv * 16 + (lid & 15);
        int t0 = c * 64 + arow;
        #pragma unroll
        for (int k = 0; k < 4; ++k)
            a1[k] = *(const bf16x8*)(x + t0 * 128 + k * 32 + kq8);

        f32x4 acc[8];
        #pragma unroll
        for (int dt = 0; dt < 8; ++dt) acc[dt] = (f32x4){0.f, 0.f, 0.f, 0.f};

        for (int sub = 0; sub < 2; ++sub) {
            int ee = 64 + sub;
            const ushort_t* gB = wgT + ee * 10240;
            const ushort_t* uB = wuT + ee * 10240;
            #pragma unroll
            for (int mi = 0; mi < 5; ++mi) {
                int boff = (mi * 16 + (lid & 15)) * 128 + kq8;
                bf16x8 bg[4], bu[4];
                #pragma unroll
                for (int k = 0; k < 4; ++k) {
                    bg[k] = *(const bf16x8*)(gB + boff + k * 32);
                    bu[k] = *(const bf16x8*)(uB + boff + k * 32);
                }
                f32x4 ag = {0.f, 0.f, 0.f, 0.f};
                f32x4 au = {0.f, 0.f, 0.f, 0.f};
                #pragma unroll
                for (int k = 0; k < 4; ++k) {
                    ag = __builtin_amdgcn_mfma_f32_16x16x32_bf16(a1[k], bg[k], ag, 0, 0, 0);
                    au = __builtin_amdgcn_mfma_f32_16x16x32_bf16(a1[k], bu[k], au, 0, 0, 0);
                }
                #pragma unroll
                for (int rg = 0; rg < 4; ++rg) {
                    float g = ag[rg], uu2 = au[rg];
                    float h = (g / (1.f + expf(-g))) * uu2;
                    int row = wv * 16 + (lid >> 4) * 4 + rg;
                    int cb = (mi * 16 + (lid & 15)) * 2;
                    *(ushort_t*)(hl + row * 256 + (cb ^ ((row & 7) << 4))) = f2bf(h);
                }
            }
            if (sub == 0 && lid < 32) {   // zero-pad own 16 rows, K cols 80..95
                int r = wv * 16 + (lid >> 1), ch = 10 + (lid & 1);
                uint4 z = {0u, 0u, 0u, 0u};
                *(uint4*)(hl + r * 256 + ((ch * 16) ^ ((r & 7) << 4))) = z;
            }
            const ushort_t* dB = wdP + ee * 12288;
            int brow = wv * 16 + (lid & 15);
            #pragma unroll
            for (int dt = 0; dt < 8; ++dt) {
                int drow = dt * 16 + (lid & 15);
                bf16x8 ad[3];
                #pragma unroll
                for (int k = 0; k < 3; ++k)
                    ad[k] = *(const bf16x8*)(dB + drow * 96 + k * 32 + kq8);
                f32x4 cc = acc[dt];
                #pragma unroll
                for (int k = 0; k < 3; ++k) {
                    bf16x8 b = *(const bf16x8*)(hl + brow * 256 + (((k * 64) + kg) ^ ((brow & 7) << 4)));
                    cc = __builtin_amdgcn_mfma_f32_16x16x32_bf16(ad[k], b, cc, 0, 0, 0);
                }
                acc[dt] = cc;
            }
        }

        int rloc = wv * 16 + (lid & 15);
        int t = c * 64 + rloc;
        if (FAST) {
            ushort_t* dst = ysh + (size_t)t * 128;
            #pragma unroll
            for (int dt = 0; dt < 8; ++dt) {
                int d0 = dt * 16 + (lid >> 4) * 4;
                ushort_t o[4];
                #pragma unroll
                for (int rg = 0; rg < 4; ++rg) o[rg] = f2bf(acc[dt][rg]);
                *(uint2*)(dst + d0) = *(const uint2*)o;
            }
        } else {
            #pragma unroll
            for (int dt = 0; dt < 8; ++dt) {
                int d0 = dt * 16 + (lid >> 4) * 4;
                #pragma unroll
                for (int rg = 0; rg < 4; ++rg)
                    atomicAdd(&ybuf[t * 128 + d0 + rg], acc[dt][rg]);
            }
        }
    }
}

// ---------------------------------------------------------------------------
// Final gather: out[t] = sum_k yperm[pos2[t*6+k]] + ysh[t].
// ---------------------------------------------------------------------------
__global__ __launch_bounds__(256) void k_final_gather(const ushort_t* yperm,
        const ushort_t* ysh, const int* pos2, void* out, const ushort_t* gwDet) {
    int idx = blockIdx.x * 256 + threadIdx.x;
    int t = idx >> 4, cg = (idx & 15) * 8;
    int f32m = detect_f32m(gwDet);
    float acc[8];
    {
        uint4 v = *(const uint4*)(ysh + (size_t)t * 128 + cg);
        const ushort_t* u = (const ushort_t*)&v;
        #pragma unroll
        for (int j = 0; j < 8; ++j) acc[j] = bf2f(u[j]);
    }
    const int* pp = pos2 + t * 6;
    #pragma unroll
    for (int k = 0; k < 6; ++k) {
        int p = pp[k];
        uint4 v = *(const uint4*)(yperm + (size_t)p * 128 + cg);
        const ushort_t* u = (const ushort_t*)&v;
        #pragma unroll
        for (int j = 0; j < 8; ++j) acc[j] += bf2f(u[j]);
    }
    if (f32m) {
        float4 o0 = {acc[0], acc[1], acc[2], acc[3]};
        float4 o1 = {acc[4], acc[5], acc[6], acc[7]};
        float* op = (float*)out + (size_t)t * 128 + cg;
        *(float4*)op = o0; *(float4*)(op + 4) = o1;
    } else {
        ushort_t o[8];
        #pragma unroll
        for (int j = 0; j < 8; ++j) o[j] = f2bf(acc[j]);
        *(uint4*)((ushort_t*)out + (size_t)t * 128 + cg) = *(const uint4*)o;
    }
}

// fallback: read fp32 ybuf
__global__ __launch_bounds__(256) void k_final_ybuf(const float* ybuf, void* out,
        const ushort_t* gwDet) {
    int i = blockIdx.x * 256 + threadIdx.x;
    int f32m = detect_f32m(gwDet);
    float4 v = ((const float4*)ybuf)[i];
    if (f32m) {
        ((float4*)out)[i] = v;
    } else {
        ushort4 o;
        o.x = f2bf(v.x); o.y = f2bf(v.y); o.z = f2bf(v.z); o.w = f2bf(v.w);
        ((ushort4*)out)[i] = o;
    }
}

// ---------------------------------------------------------------------------
extern "C" void kernel_launch(void* const* d_in, const int* in_sizes, int n_in,
                              void* d_out, int out_size, void* d_ws, size_t ws_size,
                              hipStream_t stream) {
    (void)in_sizes; (void)n_in; (void)out_size;
    const void* x   = d_in[0];
    const void* gw  = d_in[1];
    const void* wg  = d_in[2];
    const void* wu  = d_in[3];
    const void* wd  = d_in[4];
    const void* swg = d_in[5];
    const void* swu = d_in[6];
    const void* swd = d_in[7];

    char* ws = (char*)d_ws;
    int fast = (ws_size >= (size_t)NEED_FAST) ? 1 : 0;

    int*      Wi     = (int*)d_ws;
    int*      topk_i = (int*)(ws + OFF_TOPKI);
    float*    topk_w = (float*)(ws + OFF_TOPKW);
    int*      perm   = (int*)(ws + OFF_PERM);
    float*    permw  = (float*)(ws + OFF_PERMW);
    int*      pos2   = (int*)(ws + OFF_POS2);

    ushort_t* yperm = (ushort_t*)(ws + OFF_YPERM);
    ushort_t* ysh   = (ushort_t*)(ws + OFF_YSH);
    float*    ybuf  = (float*)(ws + FOFF_YBUF);
    ushort_t* wgT   = (ushort_t*)(ws + (fast ? OFF_WGT  : FOFF_WGT));
    ushort_t* wuT   = (ushort_t*)(ws + (fast ? OFF_WUT  : FOFF_WUT));
    ushort_t* wdP   = (ushort_t*)(ws + (fast ? OFF_WDP  : FOFF_WDP));
    ushort_t* xB    = (ushort_t*)(ws + (fast ? OFF_XB   : FOFF_XB));
    int*      histP = (int*)(ws + (fast ? OFF_HIST : FOFF_HIST));
    int*      boffG = (int*)(ws + (fast ? OFF_BOFF : FOFF_BOFF));

    if (!fast) hipMemsetAsync(ybuf, 0, 16384 * 128 * 4, stream);

    k_prep<<<3 * EALL * 4, 256, 0, stream>>>(wg, wu, wd, swg, swu, swd,
                                             (const ushort_t*)gw, wgT, wuT, wdP);
    k_gate<<<256, 1024, 0, stream>>>(x, gw, xB, topk_i, topk_w, histP);
    k_scan<<<1, 256, 0, stream>>>(Wi, histP, boffG);
    k_scatter<<<256, 256, 0, stream>>>(topk_i, topk_w, boffG, perm, permw, pos2);
    if (fast) {
        k_expert<1><<<1088, 256, 0, stream>>>(xB, wgT, wuT, wdP, Wi, perm, permw, yperm, ysh, ybuf);
        k_final_gather<<<1024, 256, 0, stream>>>(yperm, ysh, pos2, d_out, (const ushort_t*)gw);
    } else {
        k_expert<0><<<1088, 256, 0, stream>>>(xB, wgT, wuT, wdP, Wi, perm, permw, yperm, ysh, ybuf);
        k_final_ybuf<<<2048, 256, 0, stream>>>(ybuf, d_out, (const ushort_t*)gw);
    }
}